// Round 1
// baseline (2147.336 us; speedup 1.0000x reference)
//
#include <hip/hip_runtime.h>
#include <hip/hip_bf16.h>
#include <stdint.h>

// Problem constants (fixed by the reference)
#define N_NODES 50000
#define N_EDGES 1600000
#define IN_DIM  1024
#define HID     2048
#define OUTC    3
#define M_PAD   50048   // 391 * 128 — M padded to GEMM tile
#define BN_EPS  1e-5f

#define SCAN_CH 512
#define NCH     98      // ceil(50000/512)
#define BN_ROWS 782     // ceil(50000/64)

typedef __bf16 bf16_t;
typedef __bf16 bf16x4_t __attribute__((ext_vector_type(4)));
typedef __bf16 bf16x8_t __attribute__((ext_vector_type(8)));
typedef float  f32x4_t  __attribute__((ext_vector_type(4)));

// async global->LDS, 16B per lane. LDS layout must be contiguous in lane order.
__device__ __forceinline__ void gl2lds16(const void* g, void* l) {
  __builtin_amdgcn_global_load_lds((const __attribute__((address_space(1))) uint32_t*)g,
                                   (__attribute__((address_space(3))) uint32_t*)l,
                                   16, 0, 0);
}

// ---------- degree histograms ----------
__global__ void k_hist(const int* __restrict__ src, const int* __restrict__ dst,
                       int* out_cnt, int* in_cnt) {
  int e = blockIdx.x * 256 + threadIdx.x;
  if (e < N_EDGES) {
    atomicAdd(&out_cnt[src[e]], 1);
    atomicAdd(&in_cnt[dst[e]], 1);
  }
}

// ---------- degree norms: clip(deg,1)^-0.5 ----------
__global__ void k_norms(const int* __restrict__ out_cnt, const int* __restrict__ in_cnt,
                        float* out_norm, float* in_norm) {
  int i = blockIdx.x * 256 + threadIdx.x;
  if (i < N_NODES) {
    out_norm[i] = rsqrtf((float)max(out_cnt[i], 1));
    in_norm[i]  = rsqrtf((float)max(in_cnt[i], 1));
  }
}

// ---------- exclusive scan of in-degrees (3-phase) ----------
__global__ void k_scan1(const int* __restrict__ deg, int* incl, int* partial) {
  __shared__ int s[SCAN_CH];
  int tid = threadIdx.x;
  int i = blockIdx.x * SCAN_CH + tid;
  int v = (i < N_NODES) ? deg[i] : 0;
  s[tid] = v;
  for (int off = 1; off < SCAN_CH; off <<= 1) {
    __syncthreads();
    int x = (tid >= off) ? s[tid - off] : 0;
    __syncthreads();
    s[tid] += x;
  }
  __syncthreads();
  if (i < N_NODES) incl[i] = s[tid];
  if (tid == SCAN_CH - 1) partial[blockIdx.x] = s[tid];
}

__global__ void k_scan2(const int* __restrict__ partial, int* chunk_off, int* row_ptr) {
  if (threadIdx.x == 0 && blockIdx.x == 0) {
    int run = 0;
    for (int b = 0; b < NCH; b++) { chunk_off[b] = run; run += partial[b]; }
    row_ptr[N_NODES] = run;   // == N_EDGES
  }
}

__global__ void k_scan3(const int* __restrict__ deg, const int* __restrict__ incl,
                        const int* __restrict__ chunk_off, int* row_ptr, int* cursor) {
  int i = blockIdx.x * SCAN_CH + threadIdx.x;
  if (i < N_NODES) {
    int e = chunk_off[blockIdx.x] + incl[i] - deg[i];
    row_ptr[i] = e;
    cursor[i]  = e;
  }
}

// ---------- CSR fill (bucket by dst) ----------
__global__ void k_fill(const int* __restrict__ src, const int* __restrict__ dst,
                       int* cursor, int* csr_src) {
  int e = blockIdx.x * 256 + threadIdx.x;
  if (e < N_EDGES) {
    int p = atomicAdd(&cursor[dst[e]], 1);
    csr_src[p] = src[e];
  }
}

// ---------- layer-1 aggregation: agg[i] = in_norm[i] * sum_e out_norm[src]*x[src]  -> bf16 ----------
// one block per node (padded rows write zeros), 256 threads * float4 = 1024 feats
__global__ void k_agg1(const float* __restrict__ in_feat, const int* __restrict__ row_ptr,
                       const int* __restrict__ csr_src, const float* __restrict__ out_norm,
                       const float* __restrict__ in_norm, bf16_t* __restrict__ aggb) {
  int node = blockIdx.x;
  int tid = threadIdx.x;
  float4 acc = make_float4(0.f, 0.f, 0.f, 0.f);
  if (node < N_NODES) {
    int beg = row_ptr[node], end = row_ptr[node + 1];
    for (int e = beg; e < end; e++) {
      int s = csr_src[e];
      float c = out_norm[s];
      float4 v = *(const float4*)(in_feat + (size_t)s * IN_DIM + tid * 4);
      acc.x += c * v.x; acc.y += c * v.y; acc.z += c * v.z; acc.w += c * v.w;
    }
    float inn = in_norm[node];
    acc.x *= inn; acc.y *= inn; acc.z *= inn; acc.w *= inn;
  }
  bf16x4_t o;
  o[0] = (bf16_t)acc.x; o[1] = (bf16_t)acc.y; o[2] = (bf16_t)acc.z; o[3] = (bf16_t)acc.w;
  *(bf16x4_t*)(aggb + (size_t)node * IN_DIM + tid * 4) = o;
}

// ---------- W1 [K=1024][N=2048] fp32 -> W1t [N][K] bf16 ----------
__global__ void k_w1t(const float* __restrict__ W1, bf16_t* __restrict__ W1t) {
  int idx = blockIdx.x * 256 + threadIdx.x;   // n-major flat over [2048][1024]
  int n = idx >> 10;
  int k = idx & 1023;
  W1t[idx] = (bf16_t)W1[(size_t)k * HID + n];
}

// ---------- GEMM1: h1 = relu(agg @ W1 + b1), bf16 in/out, fp32 accum ----------
// m97 structure: 128x128 tile, BK=32, 4 waves in 2x2, 16x16x32 MFMA, global_load_lds w=16
__global__ void __launch_bounds__(256)
k_gemm1(const bf16_t* __restrict__ A, const bf16_t* __restrict__ Bt,
        const float* __restrict__ b1, bf16_t* __restrict__ C) {
  __shared__ bf16_t As[128 * 32];
  __shared__ bf16_t Bs[128 * 32];
  int t = threadIdx.x;
  const int m0 = blockIdx.x * 128, n0 = blockIdx.y * 128;

  // staging: thread t loads 16B: row = t>>2 (64 rows per inst), seg = t&3
  int lrow = t >> 2, lseg = t & 3;
  const bf16_t* aG0 = A + (size_t)(m0 + lrow) * IN_DIM + lseg * 8;
  const bf16_t* aG1 = aG0 + (size_t)64 * IN_DIM;
  const bf16_t* bG0 = Bt + (size_t)(n0 + lrow) * IN_DIM + lseg * 8;
  const bf16_t* bG1 = bG0 + (size_t)64 * IN_DIM;
  bf16_t* aL0 = As + t * 8; bf16_t* aL1 = As + 2048 + t * 8;
  bf16_t* bL0 = Bs + t * 8; bf16_t* bL1 = Bs + 2048 + t * 8;

  // wave -> 64x64 quadrant; fragment addressing per m89-verified layout
  int wv = t >> 6, ln = t & 63;
  int wm = (wv >> 1) * 64, wn = (wv & 1) * 64;
  int fr = ln & 15, fq = ln >> 4;          // A row / B col = ln&15 ; k-quad = ln>>4
  const bf16_t* aF = As + (wm + fr) * 32 + fq * 8;
  const bf16_t* bF = Bs + (wn + fr) * 32 + fq * 8;

  f32x4_t acc[4][4];
#pragma unroll
  for (int i = 0; i < 4; i++)
#pragma unroll
    for (int j = 0; j < 4; j++) { acc[i][j][0]=0.f; acc[i][j][1]=0.f; acc[i][j][2]=0.f; acc[i][j][3]=0.f; }

  for (int kt = 0; kt < IN_DIM; kt += 32) {
    __syncthreads();                 // LDS reads of previous tile done
    gl2lds16(aG0 + kt, aL0);
    gl2lds16(aG1 + kt, aL1);
    gl2lds16(bG0 + kt, bL0);
    gl2lds16(bG1 + kt, bL1);
    __syncthreads();                 // compiler drains vmcnt before barrier
    bf16x8_t af[4], bfr[4];
#pragma unroll
    for (int i = 0; i < 4; i++) af[i]  = *(const bf16x8_t*)(aF + i * 16 * 32);
#pragma unroll
    for (int j = 0; j < 4; j++) bfr[j] = *(const bf16x8_t*)(bF + j * 16 * 32);
#pragma unroll
    for (int i = 0; i < 4; i++)
#pragma unroll
      for (int j = 0; j < 4; j++)
        acc[i][j] = __builtin_amdgcn_mfma_f32_16x16x32_bf16(af[i], bfr[j], acc[i][j], 0, 0, 0);
  }

  // epilogue: C/D layout col = ln&15, row = (ln>>4)*4 + reg ; +bias, relu, bf16 store
#pragma unroll
  for (int i = 0; i < 4; i++) {
#pragma unroll
    for (int j = 0; j < 4; j++) {
      int col = n0 + wn + j * 16 + fr;
      float bias = b1[col];
#pragma unroll
      for (int r = 0; r < 4; r++) {
        int row = m0 + wm + i * 16 + fq * 4 + r;
        float v = acc[i][j][r] + bias;
        v = v > 0.f ? v : 0.f;
        C[(size_t)row * HID + col] = (bf16_t)v;
      }
    }
  }
}

// ---------- BN column stats (sum, sumsq) over first 50000 rows ----------
__global__ void k_bnstat(const bf16_t* __restrict__ h1, float* colsum, float* colsq) {
  int col = blockIdx.x * 256 + threadIdx.x;
  int r0 = blockIdx.y * BN_ROWS;
  int r1 = min(r0 + BN_ROWS, N_NODES);
  float s = 0.f, ss = 0.f;
  for (int r = r0; r < r1; r++) {
    float x = (float)h1[(size_t)r * HID + col];
    s += x; ss += x * x;
  }
  atomicAdd(&colsum[col], s);
  atomicAdd(&colsq[col], ss);
}

// ---------- fold BN into Wout: cw[f,o] = rs[f]*Wout[f,o]; mrs[f] = mean[f]*rs[f] ----------
__global__ void k_bnfin(const float* __restrict__ colsum, const float* __restrict__ colsq,
                        const float* __restrict__ Wout,
                        float* cw0, float* cw1, float* cw2, float* mrs) {
  int f = blockIdx.x * 256 + threadIdx.x;
  if (f < HID) {
    float mean = colsum[f] * (1.f / N_NODES);
    float var  = colsq[f] * (1.f / N_NODES) - mean * mean;
    float rs   = rsqrtf(var + BN_EPS);
    cw0[f] = rs * Wout[f * 3 + 0];
    cw1[f] = rs * Wout[f * 3 + 1];
    cw2[f] = rs * Wout[f * 3 + 2];
    mrs[f] = mean * rs;
  }
}

// ---------- ct[o] = sum_f mrs[f]*Wout[f,o] ----------
__global__ void k_ct(const float* __restrict__ mrs, const float* __restrict__ Wout, float* ct) {
  __shared__ float red[3][256];
  int tid = threadIdx.x;
  float s0 = 0.f, s1 = 0.f, s2 = 0.f;
  for (int f = tid; f < HID; f += 256) {
    float m = mrs[f];
    s0 += m * Wout[f * 3 + 0];
    s1 += m * Wout[f * 3 + 1];
    s2 += m * Wout[f * 3 + 2];
  }
  red[0][tid] = s0; red[1][tid] = s1; red[2][tid] = s2;
  __syncthreads();
  for (int off = 128; off; off >>= 1) {
    if (tid < off) {
      red[0][tid] += red[0][tid + off];
      red[1][tid] += red[1][tid + off];
      red[2][tid] += red[2][tid + off];
    }
    __syncthreads();
  }
  if (tid == 0) { ct[0] = red[0][0]; ct[1] = red[1][0]; ct[2] = red[2][0]; }
}

// ---------- t[n] = out_norm[n] * (h_bn[n] @ Wout) via cw/ct ----------
__global__ void k_tmat(const bf16_t* __restrict__ h1, const float* __restrict__ cw0,
                       const float* __restrict__ cw1, const float* __restrict__ cw2,
                       const float* __restrict__ ct, const float* __restrict__ out_norm,
                       float4* __restrict__ t4) {
  int n = blockIdx.x, tid = threadIdx.x;
  int f0 = tid * 8;
  bf16x8_t hv = *(const bf16x8_t*)(h1 + (size_t)n * HID + f0);
  float s0 = 0.f, s1 = 0.f, s2 = 0.f;
#pragma unroll
  for (int j = 0; j < 8; j++) {
    float h = (float)hv[j];
    s0 += h * cw0[f0 + j];
    s1 += h * cw1[f0 + j];
    s2 += h * cw2[f0 + j];
  }
#pragma unroll
  for (int off = 32; off; off >>= 1) {
    s0 += __shfl_down(s0, off);
    s1 += __shfl_down(s1, off);
    s2 += __shfl_down(s2, off);
  }
  __shared__ float red[3][4];
  int wv = tid >> 6, ln = tid & 63;
  if (ln == 0) { red[0][wv] = s0; red[1][wv] = s1; red[2][wv] = s2; }
  __syncthreads();
  if (tid == 0) {
    float r0 = red[0][0] + red[0][1] + red[0][2] + red[0][3];
    float r1 = red[1][0] + red[1][1] + red[1][2] + red[1][3];
    float r2 = red[2][0] + red[2][1] + red[2][2] + red[2][3];
    float on = out_norm[n];
    t4[n] = make_float4(on * (r0 - ct[0]), on * (r1 - ct[1]), on * (r2 - ct[2]), 0.f);
  }
}

// ---------- layer-2 aggregation (3 feats) + bias + softmax ----------
__global__ void k_out(const int* __restrict__ row_ptr, const int* __restrict__ csr_src,
                      const float4* __restrict__ t4, const float* __restrict__ in_norm,
                      const float* __restrict__ bout, float* __restrict__ out) {
  int i = blockIdx.x * 256 + threadIdx.x;
  if (i >= N_NODES) return;
  float a0 = 0.f, a1 = 0.f, a2 = 0.f;
  int beg = row_ptr[i], end = row_ptr[i + 1];
  for (int e = beg; e < end; e++) {
    float4 tv = t4[csr_src[e]];
    a0 += tv.x; a1 += tv.y; a2 += tv.z;
  }
  float inn = in_norm[i];
  float l0 = inn * a0 + bout[0];
  float l1 = inn * a1 + bout[1];
  float l2 = inn * a2 + bout[2];
  float m = fmaxf(l0, fmaxf(l1, l2));
  float e0 = expf(l0 - m), e1 = expf(l1 - m), e2 = expf(l2 - m);
  float rs = 1.f / (e0 + e1 + e2);
  out[i * 3 + 0] = e0 * rs;
  out[i * 3 + 1] = e1 * rs;
  out[i * 3 + 2] = e2 * rs;
}

extern "C" void kernel_launch(void* const* d_in, const int* in_sizes, int n_in,
                              void* d_out, int out_size, void* d_ws, size_t ws_size,
                              hipStream_t stream) {
  const float* in_feat = (const float*)d_in[0];
  const int*   src     = (const int*)d_in[1];
  const int*   dst     = (const int*)d_in[2];
  const float* W1      = (const float*)d_in[3];
  const float* b1      = (const float*)d_in[4];
  const float* Wout    = (const float*)d_in[5];
  const float* bout    = (const float*)d_in[6];
  float* out = (float*)d_out;

  char* p = (char*)d_ws;
  auto alloc = [&](size_t bytes) { char* r = p; p += (bytes + 255) & ~(size_t)255; return r; };
  bf16_t* h1      = (bf16_t*)alloc((size_t)M_PAD * HID * 2);      // 205 MB
  bf16_t* aggb    = (bf16_t*)alloc((size_t)M_PAD * IN_DIM * 2);   // 102.5 MB
  bf16_t* W1t     = (bf16_t*)alloc((size_t)HID * IN_DIM * 2);     // 4 MB
  int* csr_src    = (int*)alloc((size_t)N_EDGES * 4);             // 6.4 MB
  int* row_ptr    = (int*)alloc((size_t)(N_NODES + 1) * 4);
  int* cursor     = (int*)alloc((size_t)N_NODES * 4);
  int* incl       = (int*)alloc((size_t)N_NODES * 4);
  int* partial    = (int*)alloc((size_t)NCH * 4);
  int* chunk_off  = (int*)alloc((size_t)NCH * 4);
  int* out_cnt    = (int*)alloc((size_t)N_NODES * 4);
  int* in_cnt     = (int*)alloc((size_t)N_NODES * 4);
  float* out_norm = (float*)alloc((size_t)N_NODES * 4);
  float* in_norm  = (float*)alloc((size_t)N_NODES * 4);
  float* colsum   = (float*)alloc((size_t)HID * 4);
  float* colsq    = (float*)alloc((size_t)HID * 4);
  float* cw0      = (float*)alloc((size_t)HID * 4);
  float* cw1      = (float*)alloc((size_t)HID * 4);
  float* cw2      = (float*)alloc((size_t)HID * 4);
  float* mrs      = (float*)alloc((size_t)HID * 4);
  float* ct       = (float*)alloc(4 * 4);
  float4* t4      = (float4*)alloc((size_t)N_NODES * 16);

  // ws is poisoned 0xAA each call — zero what needs zeroing
  hipMemsetAsync(out_cnt, 0, (size_t)N_NODES * 4, stream);
  hipMemsetAsync(in_cnt,  0, (size_t)N_NODES * 4, stream);
  hipMemsetAsync(colsum,  0, (size_t)HID * 4, stream);
  hipMemsetAsync(colsq,   0, (size_t)HID * 4, stream);

  k_hist <<<(N_EDGES + 255) / 256, 256, 0, stream>>>(src, dst, out_cnt, in_cnt);
  k_norms<<<(N_NODES + 255) / 256, 256, 0, stream>>>(out_cnt, in_cnt, out_norm, in_norm);
  k_scan1<<<NCH, SCAN_CH, 0, stream>>>(in_cnt, incl, partial);
  k_scan2<<<1, 64, 0, stream>>>(partial, chunk_off, row_ptr);
  k_scan3<<<NCH, SCAN_CH, 0, stream>>>(in_cnt, incl, chunk_off, row_ptr, cursor);
  k_fill <<<(N_EDGES + 255) / 256, 256, 0, stream>>>(src, dst, cursor, csr_src);
  k_w1t  <<<(HID * IN_DIM) / 256, 256, 0, stream>>>(W1, W1t);
  k_agg1 <<<M_PAD, 256, 0, stream>>>(in_feat, row_ptr, csr_src, out_norm, in_norm, aggb);
  k_gemm1<<<dim3(M_PAD / 128, HID / 128), 256, 0, stream>>>(aggb, W1t, b1, h1);
  k_bnstat<<<dim3(HID / 256, 64), 256, 0, stream>>>(h1, colsum, colsq);
  k_bnfin<<<HID / 256, 256, 0, stream>>>(colsum, colsq, Wout, cw0, cw1, cw2, mrs);
  k_ct   <<<1, 256, 0, stream>>>(mrs, Wout, ct);
  k_tmat <<<N_NODES, 256, 0, stream>>>(h1, cw0, cw1, cw2, ct, out_norm, t4);
  k_out  <<<(N_NODES + 255) / 256, 256, 0, stream>>>(row_ptr, csr_src, t4, in_norm, bout, out);
}

// Round 2
// 1716.233 us; speedup vs baseline: 1.2512x; 1.2512x over previous
//
#include <hip/hip_runtime.h>
#include <hip/hip_bf16.h>
#include <stdint.h>

// Problem constants (fixed by the reference)
#define N_NODES 50000
#define N_EDGES 1600000
#define IN_DIM  1024
#define HID     2048
#define OUTC    3
#define M_PAD   50048   // 391 * 128 — M padded to GEMM tile
#define BN_EPS  1e-5f

#define SCAN_CH 512
#define NCH     98      // ceil(50000/512)
#define BN_ROWS 782     // ceil(50000/64)

typedef __bf16 bf16_t;
typedef __bf16 bf16x4_t __attribute__((ext_vector_type(4)));
typedef __bf16 bf16x8_t __attribute__((ext_vector_type(8)));
typedef float  f32x4_t  __attribute__((ext_vector_type(4)));

// async global->LDS, 16B per lane. LDS layout must be contiguous in lane order.
__device__ __forceinline__ void gl2lds16(const void* g, void* l) {
  __builtin_amdgcn_global_load_lds((const __attribute__((address_space(1))) uint32_t*)g,
                                   (__attribute__((address_space(3))) uint32_t*)l,
                                   16, 0, 0);
}

// ---------- degree histograms ----------
__global__ void k_hist(const int* __restrict__ src, const int* __restrict__ dst,
                       int* out_cnt, int* in_cnt) {
  int e = blockIdx.x * 256 + threadIdx.x;
  if (e < N_EDGES) {
    atomicAdd(&out_cnt[src[e]], 1);
    atomicAdd(&in_cnt[dst[e]], 1);
  }
}

// ---------- degree norms: clip(deg,1)^-0.5 ----------
__global__ void k_norms(const int* __restrict__ out_cnt, const int* __restrict__ in_cnt,
                        float* out_norm, float* in_norm) {
  int i = blockIdx.x * 256 + threadIdx.x;
  if (i < N_NODES) {
    out_norm[i] = rsqrtf((float)max(out_cnt[i], 1));
    in_norm[i]  = rsqrtf((float)max(in_cnt[i], 1));
  }
}

// ---------- exclusive scan of in-degrees (3-phase) ----------
__global__ void k_scan1(const int* __restrict__ deg, int* incl, int* partial) {
  __shared__ int s[SCAN_CH];
  int tid = threadIdx.x;
  int i = blockIdx.x * SCAN_CH + tid;
  int v = (i < N_NODES) ? deg[i] : 0;
  s[tid] = v;
  for (int off = 1; off < SCAN_CH; off <<= 1) {
    __syncthreads();
    int x = (tid >= off) ? s[tid - off] : 0;
    __syncthreads();
    s[tid] += x;
  }
  __syncthreads();
  if (i < N_NODES) incl[i] = s[tid];
  if (tid == SCAN_CH - 1) partial[blockIdx.x] = s[tid];
}

__global__ void k_scan2(const int* __restrict__ partial, int* chunk_off, int* row_ptr) {
  if (threadIdx.x == 0 && blockIdx.x == 0) {
    int run = 0;
    for (int b = 0; b < NCH; b++) { chunk_off[b] = run; run += partial[b]; }
    row_ptr[N_NODES] = run;   // == N_EDGES
  }
}

__global__ void k_scan3(const int* __restrict__ deg, const int* __restrict__ incl,
                        const int* __restrict__ chunk_off, int* row_ptr, int* cursor) {
  int i = blockIdx.x * SCAN_CH + threadIdx.x;
  if (i < N_NODES) {
    int e = chunk_off[blockIdx.x] + incl[i] - deg[i];
    row_ptr[i] = e;
    cursor[i]  = e;
  }
}

// ---------- CSR fill (bucket by dst) ----------
__global__ void k_fill(const int* __restrict__ src, const int* __restrict__ dst,
                       int* cursor, int* csr_src) {
  int e = blockIdx.x * 256 + threadIdx.x;
  if (e < N_EDGES) {
    int p = atomicAdd(&cursor[dst[e]], 1);
    csr_src[p] = src[e];
  }
}

// ---------- convert features: xb[n,f] = bf16(in_feat[n,f] * out_norm[n]) ----------
// halves gather traffic (102 MB table, fully L3-resident) and folds the per-edge scale
__global__ void k_conv(const float* __restrict__ in_feat, const float* __restrict__ out_norm,
                       bf16_t* __restrict__ xb) {
  int node = blockIdx.x, tid = threadIdx.x;
  float on = out_norm[node];
  float4 v = *(const float4*)(in_feat + (size_t)node * IN_DIM + tid * 4);
  bf16x4_t o;
  o[0] = (bf16_t)(v.x * on); o[1] = (bf16_t)(v.y * on);
  o[2] = (bf16_t)(v.z * on); o[3] = (bf16_t)(v.w * on);
  *(bf16x4_t*)(xb + (size_t)node * IN_DIM + tid * 4) = o;
}

// ---------- layer-1 aggregation on bf16 pre-scaled feats ----------
// 128 threads/block, bf16x8 (16B) per lane; edge loop unrolled x2; fp32 accum
__global__ void k_agg1(const bf16_t* __restrict__ xb, const int* __restrict__ row_ptr,
                       const int* __restrict__ csr_src, const float* __restrict__ in_norm,
                       bf16_t* __restrict__ aggb) {
  int node = blockIdx.x;
  int tid = threadIdx.x;            // 0..127
  float acc[8];
#pragma unroll
  for (int j = 0; j < 8; j++) acc[j] = 0.f;
  float inn = 0.f;
  if (node < N_NODES) {
    int beg = row_ptr[node], end = row_ptr[node + 1];
    int e = beg;
    for (; e + 2 <= end; e += 2) {
      int s0 = csr_src[e], s1 = csr_src[e + 1];
      bf16x8_t v0 = *(const bf16x8_t*)(xb + (size_t)s0 * IN_DIM + tid * 8);
      bf16x8_t v1 = *(const bf16x8_t*)(xb + (size_t)s1 * IN_DIM + tid * 8);
#pragma unroll
      for (int j = 0; j < 8; j++) acc[j] += (float)v0[j];
#pragma unroll
      for (int j = 0; j < 8; j++) acc[j] += (float)v1[j];
    }
    if (e < end) {
      int s0 = csr_src[e];
      bf16x8_t v0 = *(const bf16x8_t*)(xb + (size_t)s0 * IN_DIM + tid * 8);
#pragma unroll
      for (int j = 0; j < 8; j++) acc[j] += (float)v0[j];
    }
    inn = in_norm[node];
  }
  bf16x8_t o;
#pragma unroll
  for (int j = 0; j < 8; j++) o[j] = (bf16_t)(acc[j] * inn);
  *(bf16x8_t*)(aggb + (size_t)node * IN_DIM + tid * 8) = o;
}

// ---------- W1 [K=1024][N=2048] fp32 -> W1t [N][K] bf16, LDS-tiled transpose ----------
__global__ void k_w1t(const float* __restrict__ W1, bf16_t* __restrict__ W1t) {
  __shared__ float tile[32][33];
  int k0 = blockIdx.x * 32, n0 = blockIdx.y * 32;
  int tx = threadIdx.x & 31, ty = threadIdx.x >> 5;   // 32 x 8
#pragma unroll
  for (int r = 0; r < 32; r += 8)
    tile[ty + r][tx] = W1[(size_t)(k0 + ty + r) * HID + n0 + tx];
  __syncthreads();
#pragma unroll
  for (int r = 0; r < 32; r += 8)
    W1t[(size_t)(n0 + ty + r) * IN_DIM + k0 + tx] = (bf16_t)tile[tx][ty + r];
}

// ---------- GEMM1: h1 = relu(agg @ W1 + b1), bf16 in/out, fp32 accum ----------
// m97 structure: 128x128 tile, BK=32, 4 waves in 2x2, 16x16x32 MFMA, global_load_lds w=16
__global__ void __launch_bounds__(256)
k_gemm1(const bf16_t* __restrict__ A, const bf16_t* __restrict__ Bt,
        const float* __restrict__ b1, bf16_t* __restrict__ C) {
  __shared__ bf16_t As[128 * 32];
  __shared__ bf16_t Bs[128 * 32];
  int t = threadIdx.x;
  const int m0 = blockIdx.x * 128, n0 = blockIdx.y * 128;

  // staging: thread t loads 16B: row = t>>2 (64 rows per inst), seg = t&3
  int lrow = t >> 2, lseg = t & 3;
  const bf16_t* aG0 = A + (size_t)(m0 + lrow) * IN_DIM + lseg * 8;
  const bf16_t* aG1 = aG0 + (size_t)64 * IN_DIM;
  const bf16_t* bG0 = Bt + (size_t)(n0 + lrow) * IN_DIM + lseg * 8;
  const bf16_t* bG1 = bG0 + (size_t)64 * IN_DIM;
  bf16_t* aL0 = As + t * 8; bf16_t* aL1 = As + 2048 + t * 8;
  bf16_t* bL0 = Bs + t * 8; bf16_t* bL1 = Bs + 2048 + t * 8;

  // wave -> 64x64 quadrant; fragment addressing per m89-verified layout
  int wv = t >> 6, ln = t & 63;
  int wm = (wv >> 1) * 64, wn = (wv & 1) * 64;
  int fr = ln & 15, fq = ln >> 4;          // A row / B col = ln&15 ; k-quad = ln>>4
  const bf16_t* aF = As + (wm + fr) * 32 + fq * 8;
  const bf16_t* bF = Bs + (wn + fr) * 32 + fq * 8;

  f32x4_t acc[4][4];
#pragma unroll
  for (int i = 0; i < 4; i++)
#pragma unroll
    for (int j = 0; j < 4; j++) { acc[i][j][0]=0.f; acc[i][j][1]=0.f; acc[i][j][2]=0.f; acc[i][j][3]=0.f; }

  for (int kt = 0; kt < IN_DIM; kt += 32) {
    __syncthreads();                 // LDS reads of previous tile done
    gl2lds16(aG0 + kt, aL0);
    gl2lds16(aG1 + kt, aL1);
    gl2lds16(bG0 + kt, bL0);
    gl2lds16(bG1 + kt, bL1);
    __syncthreads();                 // compiler drains vmcnt before barrier
    bf16x8_t af[4], bfr[4];
#pragma unroll
    for (int i = 0; i < 4; i++) af[i]  = *(const bf16x8_t*)(aF + i * 16 * 32);
#pragma unroll
    for (int j = 0; j < 4; j++) bfr[j] = *(const bf16x8_t*)(bF + j * 16 * 32);
#pragma unroll
    for (int i = 0; i < 4; i++)
#pragma unroll
      for (int j = 0; j < 4; j++)
        acc[i][j] = __builtin_amdgcn_mfma_f32_16x16x32_bf16(af[i], bfr[j], acc[i][j], 0, 0, 0);
  }

  // epilogue: C/D layout col = ln&15, row = (ln>>4)*4 + reg ; +bias, relu, bf16 store
#pragma unroll
  for (int i = 0; i < 4; i++) {
#pragma unroll
    for (int j = 0; j < 4; j++) {
      int col = n0 + wn + j * 16 + fr;
      float bias = b1[col];
#pragma unroll
      for (int r = 0; r < 4; r++) {
        int row = m0 + wm + i * 16 + fq * 4 + r;
        float v = acc[i][j][r] + bias;
        v = v > 0.f ? v : 0.f;
        C[(size_t)row * HID + col] = (bf16_t)v;
      }
    }
  }
}

// ---------- BN column stats (sum, sumsq) over first 50000 rows ----------
__global__ void k_bnstat(const bf16_t* __restrict__ h1, float* colsum, float* colsq) {
  int col = blockIdx.x * 256 + threadIdx.x;
  int r0 = blockIdx.y * BN_ROWS;
  int r1 = min(r0 + BN_ROWS, N_NODES);
  float s = 0.f, ss = 0.f;
  for (int r = r0; r < r1; r++) {
    float x = (float)h1[(size_t)r * HID + col];
    s += x; ss += x * x;
  }
  atomicAdd(&colsum[col], s);
  atomicAdd(&colsq[col], ss);
}

// ---------- fold BN into Wout: cw[f,o] = rs[f]*Wout[f,o]; mrs[f] = mean[f]*rs[f] ----------
__global__ void k_bnfin(const float* __restrict__ colsum, const float* __restrict__ colsq,
                        const float* __restrict__ Wout,
                        float* cw0, float* cw1, float* cw2, float* mrs) {
  int f = blockIdx.x * 256 + threadIdx.x;
  if (f < HID) {
    float mean = colsum[f] * (1.f / N_NODES);
    float var  = colsq[f] * (1.f / N_NODES) - mean * mean;
    float rs   = rsqrtf(var + BN_EPS);
    cw0[f] = rs * Wout[f * 3 + 0];
    cw1[f] = rs * Wout[f * 3 + 1];
    cw2[f] = rs * Wout[f * 3 + 2];
    mrs[f] = mean * rs;
  }
}

// ---------- ct[o] = sum_f mrs[f]*Wout[f,o] ----------
__global__ void k_ct(const float* __restrict__ mrs, const float* __restrict__ Wout, float* ct) {
  __shared__ float red[3][256];
  int tid = threadIdx.x;
  float s0 = 0.f, s1 = 0.f, s2 = 0.f;
  for (int f = tid; f < HID; f += 256) {
    float m = mrs[f];
    s0 += m * Wout[f * 3 + 0];
    s1 += m * Wout[f * 3 + 1];
    s2 += m * Wout[f * 3 + 2];
  }
  red[0][tid] = s0; red[1][tid] = s1; red[2][tid] = s2;
  __syncthreads();
  for (int off = 128; off; off >>= 1) {
    if (tid < off) {
      red[0][tid] += red[0][tid + off];
      red[1][tid] += red[1][tid + off];
      red[2][tid] += red[2][tid + off];
    }
    __syncthreads();
  }
  if (tid == 0) { ct[0] = red[0][0]; ct[1] = red[1][0]; ct[2] = red[2][0]; }
}

// ---------- t[n] = out_norm[n] * (h_bn[n] @ Wout) via cw/ct ----------
__global__ void k_tmat(const bf16_t* __restrict__ h1, const float* __restrict__ cw0,
                       const float* __restrict__ cw1, const float* __restrict__ cw2,
                       const float* __restrict__ ct, const float* __restrict__ out_norm,
                       float4* __restrict__ t4) {
  int n = blockIdx.x, tid = threadIdx.x;
  int f0 = tid * 8;
  bf16x8_t hv = *(const bf16x8_t*)(h1 + (size_t)n * HID + f0);
  float s0 = 0.f, s1 = 0.f, s2 = 0.f;
#pragma unroll
  for (int j = 0; j < 8; j++) {
    float h = (float)hv[j];
    s0 += h * cw0[f0 + j];
    s1 += h * cw1[f0 + j];
    s2 += h * cw2[f0 + j];
  }
#pragma unroll
  for (int off = 32; off; off >>= 1) {
    s0 += __shfl_down(s0, off);
    s1 += __shfl_down(s1, off);
    s2 += __shfl_down(s2, off);
  }
  __shared__ float red[3][4];
  int wv = tid >> 6, ln = tid & 63;
  if (ln == 0) { red[0][wv] = s0; red[1][wv] = s1; red[2][wv] = s2; }
  __syncthreads();
  if (tid == 0) {
    float r0 = red[0][0] + red[0][1] + red[0][2] + red[0][3];
    float r1 = red[1][0] + red[1][1] + red[1][2] + red[1][3];
    float r2 = red[2][0] + red[2][1] + red[2][2] + red[2][3];
    float on = out_norm[n];
    t4[n] = make_float4(on * (r0 - ct[0]), on * (r1 - ct[1]), on * (r2 - ct[2]), 0.f);
  }
}

// ---------- layer-2 aggregation (3 feats) + bias + softmax ----------
__global__ void k_out(const int* __restrict__ row_ptr, const int* __restrict__ csr_src,
                      const float4* __restrict__ t4, const float* __restrict__ in_norm,
                      const float* __restrict__ bout, float* __restrict__ out) {
  int i = blockIdx.x * 256 + threadIdx.x;
  if (i >= N_NODES) return;
  float a0 = 0.f, a1 = 0.f, a2 = 0.f;
  int beg = row_ptr[i], end = row_ptr[i + 1];
  for (int e = beg; e < end; e++) {
    float4 tv = t4[csr_src[e]];
    a0 += tv.x; a1 += tv.y; a2 += tv.z;
  }
  float inn = in_norm[i];
  float l0 = inn * a0 + bout[0];
  float l1 = inn * a1 + bout[1];
  float l2 = inn * a2 + bout[2];
  float m = fmaxf(l0, fmaxf(l1, l2));
  float e0 = expf(l0 - m), e1 = expf(l1 - m), e2 = expf(l2 - m);
  float rs = 1.f / (e0 + e1 + e2);
  out[i * 3 + 0] = e0 * rs;
  out[i * 3 + 1] = e1 * rs;
  out[i * 3 + 2] = e2 * rs;
}

extern "C" void kernel_launch(void* const* d_in, const int* in_sizes, int n_in,
                              void* d_out, int out_size, void* d_ws, size_t ws_size,
                              hipStream_t stream) {
  const float* in_feat = (const float*)d_in[0];
  const int*   src     = (const int*)d_in[1];
  const int*   dst     = (const int*)d_in[2];
  const float* W1      = (const float*)d_in[3];
  const float* b1      = (const float*)d_in[4];
  const float* Wout    = (const float*)d_in[5];
  const float* bout    = (const float*)d_in[6];
  float* out = (float*)d_out;

  char* p = (char*)d_ws;
  auto alloc = [&](size_t bytes) { char* r = p; p += (bytes + 255) & ~(size_t)255; return r; };
  bf16_t* h1      = (bf16_t*)alloc((size_t)M_PAD * HID * 2);      // 205 MB
  bf16_t* aggb    = (bf16_t*)alloc((size_t)M_PAD * IN_DIM * 2);   // 102.5 MB
  bf16_t* xb      = (bf16_t*)alloc((size_t)N_NODES * IN_DIM * 2); // 102.4 MB
  bf16_t* W1t     = (bf16_t*)alloc((size_t)HID * IN_DIM * 2);     // 4 MB
  int* csr_src    = (int*)alloc((size_t)N_EDGES * 4);             // 6.4 MB
  int* row_ptr    = (int*)alloc((size_t)(N_NODES + 1) * 4);
  int* cursor     = (int*)alloc((size_t)N_NODES * 4);
  int* incl       = (int*)alloc((size_t)N_NODES * 4);
  int* partial    = (int*)alloc((size_t)NCH * 4);
  int* chunk_off  = (int*)alloc((size_t)NCH * 4);
  int* out_cnt    = (int*)alloc((size_t)N_NODES * 4);
  int* in_cnt     = (int*)alloc((size_t)N_NODES * 4);
  float* out_norm = (float*)alloc((size_t)N_NODES * 4);
  float* in_norm  = (float*)alloc((size_t)N_NODES * 4);
  float* colsum   = (float*)alloc((size_t)HID * 4);
  float* colsq    = (float*)alloc((size_t)HID * 4);
  float* cw0      = (float*)alloc((size_t)HID * 4);
  float* cw1      = (float*)alloc((size_t)HID * 4);
  float* cw2      = (float*)alloc((size_t)HID * 4);
  float* mrs      = (float*)alloc((size_t)HID * 4);
  float* ct       = (float*)alloc(4 * 4);
  float4* t4      = (float4*)alloc((size_t)N_NODES * 16);

  // ws is poisoned 0xAA each call — zero what needs zeroing
  hipMemsetAsync(out_cnt, 0, (size_t)N_NODES * 4, stream);
  hipMemsetAsync(in_cnt,  0, (size_t)N_NODES * 4, stream);
  hipMemsetAsync(colsum,  0, (size_t)HID * 4, stream);
  hipMemsetAsync(colsq,   0, (size_t)HID * 4, stream);

  k_hist <<<(N_EDGES + 255) / 256, 256, 0, stream>>>(src, dst, out_cnt, in_cnt);
  k_norms<<<(N_NODES + 255) / 256, 256, 0, stream>>>(out_cnt, in_cnt, out_norm, in_norm);
  k_conv <<<N_NODES, 256, 0, stream>>>(in_feat, out_norm, xb);
  k_scan1<<<NCH, SCAN_CH, 0, stream>>>(in_cnt, incl, partial);
  k_scan2<<<1, 64, 0, stream>>>(partial, chunk_off, row_ptr);
  k_scan3<<<NCH, SCAN_CH, 0, stream>>>(in_cnt, incl, chunk_off, row_ptr, cursor);
  k_fill <<<(N_EDGES + 255) / 256, 256, 0, stream>>>(src, dst, cursor, csr_src);
  k_w1t  <<<dim3(IN_DIM / 32, HID / 32), 256, 0, stream>>>(W1, W1t);
  k_agg1 <<<M_PAD, 128, 0, stream>>>(xb, row_ptr, csr_src, in_norm, aggb);
  k_gemm1<<<dim3(M_PAD / 128, HID / 128), 256, 0, stream>>>(aggb, W1t, b1, h1);
  k_bnstat<<<dim3(HID / 256, 64), 256, 0, stream>>>(h1, colsum, colsq);
  k_bnfin<<<HID / 256, 256, 0, stream>>>(colsum, colsq, Wout, cw0, cw1, cw2, mrs);
  k_ct   <<<1, 256, 0, stream>>>(mrs, Wout, ct);
  k_tmat <<<N_NODES, 256, 0, stream>>>(h1, cw0, cw1, cw2, ct, out_norm, t4);
  k_out  <<<(N_NODES + 255) / 256, 256, 0, stream>>>(row_ptr, csr_src, t4, in_norm, bout, out);
}

// Round 3
// 1514.042 us; speedup vs baseline: 1.4183x; 1.1335x over previous
//
#include <hip/hip_runtime.h>
#include <hip/hip_bf16.h>
#include <stdint.h>

// Problem constants (fixed by the reference)
#define N_NODES 50000
#define N_EDGES 1600000
#define IN_DIM  1024
#define HID     2048
#define OUTC    3
#define M_PAD   50048   // 391 * 128 — M padded to GEMM tile
#define BN_EPS  1e-5f

#define SCAN_CH 512
#define NCH     98      // ceil(50000/512)

typedef __bf16 bf16_t;
typedef __bf16 bf16x4_t __attribute__((ext_vector_type(4)));
typedef __bf16 bf16x8_t __attribute__((ext_vector_type(8)));
typedef float  f32x4_t  __attribute__((ext_vector_type(4)));

// async global->LDS, 16B per lane. LDS layout must be contiguous in lane order.
__device__ __forceinline__ void gl2lds16(const void* g, void* l) {
  __builtin_amdgcn_global_load_lds((const __attribute__((address_space(1))) uint32_t*)g,
                                   (__attribute__((address_space(3))) uint32_t*)l,
                                   16, 0, 0);
}

// ---------- degree histograms ----------
__global__ void k_hist(const int* __restrict__ src, const int* __restrict__ dst,
                       int* out_cnt, int* in_cnt) {
  int e = blockIdx.x * 256 + threadIdx.x;
  if (e < N_EDGES) {
    atomicAdd(&out_cnt[src[e]], 1);
    atomicAdd(&in_cnt[dst[e]], 1);
  }
}

// ---------- degree norms: clip(deg,1)^-0.5 ----------
__global__ void k_norms(const int* __restrict__ out_cnt, const int* __restrict__ in_cnt,
                        float* out_norm, float* in_norm) {
  int i = blockIdx.x * 256 + threadIdx.x;
  if (i < N_NODES) {
    out_norm[i] = rsqrtf((float)max(out_cnt[i], 1));
    in_norm[i]  = rsqrtf((float)max(in_cnt[i], 1));
  }
}

// ---------- exclusive scan of in-degrees (3-phase) ----------
__global__ void k_scan1(const int* __restrict__ deg, int* incl, int* partial) {
  __shared__ int s[SCAN_CH];
  int tid = threadIdx.x;
  int i = blockIdx.x * SCAN_CH + tid;
  int v = (i < N_NODES) ? deg[i] : 0;
  s[tid] = v;
  for (int off = 1; off < SCAN_CH; off <<= 1) {
    __syncthreads();
    int x = (tid >= off) ? s[tid - off] : 0;
    __syncthreads();
    s[tid] += x;
  }
  __syncthreads();
  if (i < N_NODES) incl[i] = s[tid];
  if (tid == SCAN_CH - 1) partial[blockIdx.x] = s[tid];
}

__global__ void k_scan2(const int* __restrict__ partial, int* chunk_off, int* row_ptr) {
  if (threadIdx.x == 0 && blockIdx.x == 0) {
    int run = 0;
    for (int b = 0; b < NCH; b++) { chunk_off[b] = run; run += partial[b]; }
    row_ptr[N_NODES] = run;   // == N_EDGES
  }
}

__global__ void k_scan3(const int* __restrict__ deg, const int* __restrict__ incl,
                        const int* __restrict__ chunk_off, int* row_ptr, int* cursor) {
  int i = blockIdx.x * SCAN_CH + threadIdx.x;
  if (i < N_NODES) {
    int e = chunk_off[blockIdx.x] + incl[i] - deg[i];
    row_ptr[i] = e;
    cursor[i]  = e;
  }
}

// ---------- CSR fill (bucket by dst) ----------
__global__ void k_fill(const int* __restrict__ src, const int* __restrict__ dst,
                       int* cursor, int* csr_src) {
  int e = blockIdx.x * 256 + threadIdx.x;
  if (e < N_EDGES) {
    int p = atomicAdd(&cursor[dst[e]], 1);
    csr_src[p] = src[e];
  }
}

// ---------- convert features: xb[n,f] = bf16(in_feat[n,f] * out_norm[n]) ----------
// halves gather traffic (102 MB table, fully L3-resident) and folds the per-edge scale
__global__ void k_conv(const float* __restrict__ in_feat, const float* __restrict__ out_norm,
                       bf16_t* __restrict__ xb) {
  int node = blockIdx.x, tid = threadIdx.x;
  float on = out_norm[node];
  float4 v = *(const float4*)(in_feat + (size_t)node * IN_DIM + tid * 4);
  bf16x4_t o;
  o[0] = (bf16_t)(v.x * on); o[1] = (bf16_t)(v.y * on);
  o[2] = (bf16_t)(v.z * on); o[3] = (bf16_t)(v.w * on);
  *(bf16x4_t*)(xb + (size_t)node * IN_DIM + tid * 4) = o;
}

// ---------- layer-1 aggregation on bf16 pre-scaled feats ----------
// 128 threads/block, bf16x8 (16B) per lane; 8-deep edge unroll for MLP; fp32 accum
__global__ void k_agg1(const bf16_t* __restrict__ xb, const int* __restrict__ row_ptr,
                       const int* __restrict__ csr_src, const float* __restrict__ in_norm,
                       bf16_t* __restrict__ aggb) {
  int node = blockIdx.x;
  int tid = threadIdx.x;            // 0..127
  float acc[8];
#pragma unroll
  for (int j = 0; j < 8; j++) acc[j] = 0.f;
  float inn = 0.f;
  if (node < N_NODES) {
    int beg = row_ptr[node], end = row_ptr[node + 1];
    int e = beg;
    // 8-deep: 8 independent 16B loads in flight per lane
    for (; e + 8 <= end; e += 8) {
      int s[8];
#pragma unroll
      for (int u = 0; u < 8; u++) s[u] = csr_src[e + u];
      bf16x8_t v[8];
#pragma unroll
      for (int u = 0; u < 8; u++)
        v[u] = *(const bf16x8_t*)(xb + (size_t)s[u] * IN_DIM + tid * 8);
#pragma unroll
      for (int u = 0; u < 8; u++)
#pragma unroll
        for (int j = 0; j < 8; j++) acc[j] += (float)v[u][j];
    }
    for (; e + 2 <= end; e += 2) {
      int s0 = csr_src[e], s1 = csr_src[e + 1];
      bf16x8_t v0 = *(const bf16x8_t*)(xb + (size_t)s0 * IN_DIM + tid * 8);
      bf16x8_t v1 = *(const bf16x8_t*)(xb + (size_t)s1 * IN_DIM + tid * 8);
#pragma unroll
      for (int j = 0; j < 8; j++) acc[j] += (float)v0[j];
#pragma unroll
      for (int j = 0; j < 8; j++) acc[j] += (float)v1[j];
    }
    if (e < end) {
      int s0 = csr_src[e];
      bf16x8_t v0 = *(const bf16x8_t*)(xb + (size_t)s0 * IN_DIM + tid * 8);
#pragma unroll
      for (int j = 0; j < 8; j++) acc[j] += (float)v0[j];
    }
    inn = in_norm[node];
  }
  bf16x8_t o;
#pragma unroll
  for (int j = 0; j < 8; j++) o[j] = (bf16_t)(acc[j] * inn);
  *(bf16x8_t*)(aggb + (size_t)node * IN_DIM + tid * 8) = o;
}

// ---------- W1 [K=1024][N=2048] fp32 -> W1t [N][K] bf16, LDS-tiled transpose ----------
__global__ void k_w1t(const float* __restrict__ W1, bf16_t* __restrict__ W1t) {
  __shared__ float tile[32][33];
  int k0 = blockIdx.x * 32, n0 = blockIdx.y * 32;
  int tx = threadIdx.x & 31, ty = threadIdx.x >> 5;   // 32 x 8
#pragma unroll
  for (int r = 0; r < 32; r += 8)
    tile[ty + r][tx] = W1[(size_t)(k0 + ty + r) * HID + n0 + tx];
  __syncthreads();
#pragma unroll
  for (int r = 0; r < 32; r += 8)
    W1t[(size_t)(n0 + ty + r) * IN_DIM + k0 + tx] = (bf16_t)tile[tx][ty + r];
}

// ---------- GEMM1: h1 = relu(agg @ W1 + b1) + fused BN column stats ----------
// m97 structure: 128x128 tile, BK=32, 4 waves in 2x2, 16x16x32 MFMA, global_load_lds w=16
__global__ void __launch_bounds__(256)
k_gemm1(const bf16_t* __restrict__ A, const bf16_t* __restrict__ Bt,
        const float* __restrict__ b1, bf16_t* __restrict__ C,
        float* __restrict__ colsum, float* __restrict__ colsq) {
  __shared__ bf16_t As[128 * 32];
  __shared__ bf16_t Bs[128 * 32];
  int t = threadIdx.x;
  const int m0 = blockIdx.x * 128, n0 = blockIdx.y * 128;

  // staging: thread t loads 16B: row = t>>2 (64 rows per inst), seg = t&3
  int lrow = t >> 2, lseg = t & 3;
  const bf16_t* aG0 = A + (size_t)(m0 + lrow) * IN_DIM + lseg * 8;
  const bf16_t* aG1 = aG0 + (size_t)64 * IN_DIM;
  const bf16_t* bG0 = Bt + (size_t)(n0 + lrow) * IN_DIM + lseg * 8;
  const bf16_t* bG1 = bG0 + (size_t)64 * IN_DIM;
  bf16_t* aL0 = As + t * 8; bf16_t* aL1 = As + 2048 + t * 8;
  bf16_t* bL0 = Bs + t * 8; bf16_t* bL1 = Bs + 2048 + t * 8;

  // wave -> 64x64 quadrant; fragment addressing per m89-verified layout
  int wv = t >> 6, ln = t & 63;
  int wm = (wv >> 1) * 64, wn = (wv & 1) * 64;
  int fr = ln & 15, fq = ln >> 4;          // A row / B col = ln&15 ; k-quad = ln>>4
  const bf16_t* aF = As + (wm + fr) * 32 + fq * 8;
  const bf16_t* bF = Bs + (wn + fr) * 32 + fq * 8;

  f32x4_t acc[4][4];
#pragma unroll
  for (int i = 0; i < 4; i++)
#pragma unroll
    for (int j = 0; j < 4; j++) { acc[i][j][0]=0.f; acc[i][j][1]=0.f; acc[i][j][2]=0.f; acc[i][j][3]=0.f; }

  for (int kt = 0; kt < IN_DIM; kt += 32) {
    __syncthreads();                 // LDS reads of previous tile done
    gl2lds16(aG0 + kt, aL0);
    gl2lds16(aG1 + kt, aL1);
    gl2lds16(bG0 + kt, bL0);
    gl2lds16(bG1 + kt, bL1);
    __syncthreads();                 // compiler drains vmcnt before barrier
    bf16x8_t af[4], bfr[4];
#pragma unroll
    for (int i = 0; i < 4; i++) af[i]  = *(const bf16x8_t*)(aF + i * 16 * 32);
#pragma unroll
    for (int j = 0; j < 4; j++) bfr[j] = *(const bf16x8_t*)(bF + j * 16 * 32);
#pragma unroll
    for (int i = 0; i < 4; i++)
#pragma unroll
      for (int j = 0; j < 4; j++)
        acc[i][j] = __builtin_amdgcn_mfma_f32_16x16x32_bf16(af[i], bfr[j], acc[i][j], 0, 0, 0);
  }

  // epilogue: C/D layout col = ln&15, row = (ln>>4)*4 + reg ; +bias, relu, bf16 store,
  // fused BN column stats (masked to valid rows), xor-shuffle reduce over k-quads
#pragma unroll
  for (int j = 0; j < 4; j++) {
    int col = n0 + wn + j * 16 + fr;
    float bias = b1[col];
    float s = 0.f, ss = 0.f;
#pragma unroll
    for (int i = 0; i < 4; i++) {
#pragma unroll
      for (int r = 0; r < 4; r++) {
        int row = m0 + wm + i * 16 + fq * 4 + r;
        float v = acc[i][j][r] + bias;
        v = v > 0.f ? v : 0.f;
        C[(size_t)row * HID + col] = (bf16_t)v;
        if (row < N_NODES) { s += v; ss += v * v; }
      }
    }
    s  += __shfl_xor(s, 16);  s  += __shfl_xor(s, 32);
    ss += __shfl_xor(ss, 16); ss += __shfl_xor(ss, 32);
    if (fq == 0) {
      atomicAdd(&colsum[col], s);
      atomicAdd(&colsq[col], ss);
    }
  }
}

// ---------- fold BN into Wout: cw[f,o] = rs[f]*Wout[f,o]; mrs[f] = mean[f]*rs[f] ----------
__global__ void k_bnfin(const float* __restrict__ colsum, const float* __restrict__ colsq,
                        const float* __restrict__ Wout,
                        float* cw0, float* cw1, float* cw2, float* mrs) {
  int f = blockIdx.x * 256 + threadIdx.x;
  if (f < HID) {
    float mean = colsum[f] * (1.f / N_NODES);
    float var  = colsq[f] * (1.f / N_NODES) - mean * mean;
    float rs   = rsqrtf(var + BN_EPS);
    cw0[f] = rs * Wout[f * 3 + 0];
    cw1[f] = rs * Wout[f * 3 + 1];
    cw2[f] = rs * Wout[f * 3 + 2];
    mrs[f] = mean * rs;
  }
}

// ---------- ct[o] = sum_f mrs[f]*Wout[f,o] ----------
__global__ void k_ct(const float* __restrict__ mrs, const float* __restrict__ Wout, float* ct) {
  __shared__ float red[3][256];
  int tid = threadIdx.x;
  float s0 = 0.f, s1 = 0.f, s2 = 0.f;
  for (int f = tid; f < HID; f += 256) {
    float m = mrs[f];
    s0 += m * Wout[f * 3 + 0];
    s1 += m * Wout[f * 3 + 1];
    s2 += m * Wout[f * 3 + 2];
  }
  red[0][tid] = s0; red[1][tid] = s1; red[2][tid] = s2;
  __syncthreads();
  for (int off = 128; off; off >>= 1) {
    if (tid < off) {
      red[0][tid] += red[0][tid + off];
      red[1][tid] += red[1][tid + off];
      red[2][tid] += red[2][tid + off];
    }
    __syncthreads();
  }
  if (tid == 0) { ct[0] = red[0][0]; ct[1] = red[1][0]; ct[2] = red[2][0]; }
}

// ---------- t[n] = out_norm[n] * (h_bn[n] @ Wout) via cw/ct ----------
__global__ void k_tmat(const bf16_t* __restrict__ h1, const float* __restrict__ cw0,
                       const float* __restrict__ cw1, const float* __restrict__ cw2,
                       const float* __restrict__ ct, const float* __restrict__ out_norm,
                       float4* __restrict__ t4) {
  int n = blockIdx.x, tid = threadIdx.x;
  int f0 = tid * 8;
  bf16x8_t hv = *(const bf16x8_t*)(h1 + (size_t)n * HID + f0);
  float s0 = 0.f, s1 = 0.f, s2 = 0.f;
#pragma unroll
  for (int j = 0; j < 8; j++) {
    float h = (float)hv[j];
    s0 += h * cw0[f0 + j];
    s1 += h * cw1[f0 + j];
    s2 += h * cw2[f0 + j];
  }
#pragma unroll
  for (int off = 32; off; off >>= 1) {
    s0 += __shfl_down(s0, off);
    s1 += __shfl_down(s1, off);
    s2 += __shfl_down(s2, off);
  }
  __shared__ float red[3][4];
  int wv = tid >> 6, ln = tid & 63;
  if (ln == 0) { red[0][wv] = s0; red[1][wv] = s1; red[2][wv] = s2; }
  __syncthreads();
  if (tid == 0) {
    float r0 = red[0][0] + red[0][1] + red[0][2] + red[0][3];
    float r1 = red[1][0] + red[1][1] + red[1][2] + red[1][3];
    float r2 = red[2][0] + red[2][1] + red[2][2] + red[2][3];
    float on = out_norm[n];
    t4[n] = make_float4(on * (r0 - ct[0]), on * (r1 - ct[1]), on * (r2 - ct[2]), 0.f);
  }
}

// ---------- layer-2 aggregation (3 feats) + bias + softmax ----------
__global__ void k_out(const int* __restrict__ row_ptr, const int* __restrict__ csr_src,
                      const float4* __restrict__ t4, const float* __restrict__ in_norm,
                      const float* __restrict__ bout, float* __restrict__ out) {
  int i = blockIdx.x * 256 + threadIdx.x;
  if (i >= N_NODES) return;
  float a0 = 0.f, a1 = 0.f, a2 = 0.f;
  int beg = row_ptr[i], end = row_ptr[i + 1];
  for (int e = beg; e < end; e++) {
    float4 tv = t4[csr_src[e]];
    a0 += tv.x; a1 += tv.y; a2 += tv.z;
  }
  float inn = in_norm[i];
  float l0 = inn * a0 + bout[0];
  float l1 = inn * a1 + bout[1];
  float l2 = inn * a2 + bout[2];
  float m = fmaxf(l0, fmaxf(l1, l2));
  float e0 = expf(l0 - m), e1 = expf(l1 - m), e2 = expf(l2 - m);
  float rs = 1.f / (e0 + e1 + e2);
  out[i * 3 + 0] = e0 * rs;
  out[i * 3 + 1] = e1 * rs;
  out[i * 3 + 2] = e2 * rs;
}

extern "C" void kernel_launch(void* const* d_in, const int* in_sizes, int n_in,
                              void* d_out, int out_size, void* d_ws, size_t ws_size,
                              hipStream_t stream) {
  const float* in_feat = (const float*)d_in[0];
  const int*   src     = (const int*)d_in[1];
  const int*   dst     = (const int*)d_in[2];
  const float* W1      = (const float*)d_in[3];
  const float* b1      = (const float*)d_in[4];
  const float* Wout    = (const float*)d_in[5];
  const float* bout    = (const float*)d_in[6];
  float* out = (float*)d_out;

  char* p = (char*)d_ws;
  auto alloc = [&](size_t bytes) { char* r = p; p += (bytes + 255) & ~(size_t)255; return r; };
  bf16_t* h1      = (bf16_t*)alloc((size_t)M_PAD * HID * 2);      // 205 MB
  bf16_t* aggb    = (bf16_t*)alloc((size_t)M_PAD * IN_DIM * 2);   // 102.5 MB
  bf16_t* xb      = (bf16_t*)alloc((size_t)N_NODES * IN_DIM * 2); // 102.4 MB
  bf16_t* W1t     = (bf16_t*)alloc((size_t)HID * IN_DIM * 2);     // 4 MB
  int* csr_src    = (int*)alloc((size_t)N_EDGES * 4);             // 6.4 MB
  int* row_ptr    = (int*)alloc((size_t)(N_NODES + 1) * 4);
  int* cursor     = (int*)alloc((size_t)N_NODES * 4);
  int* incl       = (int*)alloc((size_t)N_NODES * 4);
  int* partial    = (int*)alloc((size_t)NCH * 4);
  int* chunk_off  = (int*)alloc((size_t)NCH * 4);
  int* out_cnt    = (int*)alloc((size_t)N_NODES * 4);
  int* in_cnt     = (int*)alloc((size_t)N_NODES * 4);
  float* out_norm = (float*)alloc((size_t)N_NODES * 4);
  float* in_norm  = (float*)alloc((size_t)N_NODES * 4);
  float* colsum   = (float*)alloc((size_t)HID * 4);
  float* colsq    = (float*)alloc((size_t)HID * 4);
  float* cw0      = (float*)alloc((size_t)HID * 4);
  float* cw1      = (float*)alloc((size_t)HID * 4);
  float* cw2      = (float*)alloc((size_t)HID * 4);
  float* mrs      = (float*)alloc((size_t)HID * 4);
  float* ct       = (float*)alloc(4 * 4);
  float4* t4      = (float4*)alloc((size_t)N_NODES * 16);

  // ws is poisoned 0xAA each call — zero what needs zeroing
  hipMemsetAsync(out_cnt, 0, (size_t)N_NODES * 4, stream);
  hipMemsetAsync(in_cnt,  0, (size_t)N_NODES * 4, stream);
  hipMemsetAsync(colsum,  0, (size_t)HID * 4, stream);
  hipMemsetAsync(colsq,   0, (size_t)HID * 4, stream);

  k_hist <<<(N_EDGES + 255) / 256, 256, 0, stream>>>(src, dst, out_cnt, in_cnt);
  k_norms<<<(N_NODES + 255) / 256, 256, 0, stream>>>(out_cnt, in_cnt, out_norm, in_norm);
  k_conv <<<N_NODES, 256, 0, stream>>>(in_feat, out_norm, xb);
  k_scan1<<<NCH, SCAN_CH, 0, stream>>>(in_cnt, incl, partial);
  k_scan2<<<1, 64, 0, stream>>>(partial, chunk_off, row_ptr);
  k_scan3<<<NCH, SCAN_CH, 0, stream>>>(in_cnt, incl, chunk_off, row_ptr, cursor);
  k_fill <<<(N_EDGES + 255) / 256, 256, 0, stream>>>(src, dst, cursor, csr_src);
  k_w1t  <<<dim3(IN_DIM / 32, HID / 32), 256, 0, stream>>>(W1, W1t);
  k_agg1 <<<M_PAD, 128, 0, stream>>>(xb, row_ptr, csr_src, in_norm, aggb);
  k_gemm1<<<dim3(M_PAD / 128, HID / 128), 256, 0, stream>>>(aggb, W1t, b1, h1, colsum, colsq);
  k_bnfin<<<HID / 256, 256, 0, stream>>>(colsum, colsq, Wout, cw0, cw1, cw2, mrs);
  k_ct   <<<1, 256, 0, stream>>>(mrs, Wout, ct);
  k_tmat <<<N_NODES, 256, 0, stream>>>(h1, cw0, cw1, cw2, ct, out_norm, t4);
  k_out  <<<(N_NODES + 255) / 256, 256, 0, stream>>>(row_ptr, csr_src, t4, in_norm, bout, out);
}

// Round 4
// 1463.966 us; speedup vs baseline: 1.4668x; 1.0342x over previous
//
#include <hip/hip_runtime.h>
#include <hip/hip_bf16.h>
#include <stdint.h>

// Problem constants (fixed by the reference)
#define N_NODES 50000
#define N_EDGES 1600000
#define IN_DIM  1024
#define HID     2048
#define OUTC    3
#define M_PAD   50048   // 391 * 128 — M padded to GEMM tile
#define BN_EPS  1e-5f

#define SCAN_CH 512
#define NCH     98      // ceil(50000/512)

typedef __bf16 bf16_t;
typedef __bf16 bf16x4_t __attribute__((ext_vector_type(4)));
typedef __bf16 bf16x8_t __attribute__((ext_vector_type(8)));
typedef float  f32x4_t  __attribute__((ext_vector_type(4)));

// async global->LDS, 16B per lane. LDS layout must be contiguous in lane order.
__device__ __forceinline__ void gl2lds16(const void* g, void* l) {
  __builtin_amdgcn_global_load_lds((const __attribute__((address_space(1))) uint32_t*)g,
                                   (__attribute__((address_space(3))) uint32_t*)l,
                                   16, 0, 0);
}

// ---------- degree histograms ----------
__global__ void k_hist(const int* __restrict__ src, const int* __restrict__ dst,
                       int* out_cnt, int* in_cnt) {
  int e = blockIdx.x * 256 + threadIdx.x;
  if (e < N_EDGES) {
    atomicAdd(&out_cnt[src[e]], 1);
    atomicAdd(&in_cnt[dst[e]], 1);
  }
}

// ---------- degree norms: clip(deg,1)^-0.5 ----------
__global__ void k_norms(const int* __restrict__ out_cnt, const int* __restrict__ in_cnt,
                        float* out_norm, float* in_norm) {
  int i = blockIdx.x * 256 + threadIdx.x;
  if (i < N_NODES) {
    out_norm[i] = rsqrtf((float)max(out_cnt[i], 1));
    in_norm[i]  = rsqrtf((float)max(in_cnt[i], 1));
  }
}

// ---------- exclusive scan of in-degrees (3-phase) ----------
__global__ void k_scan1(const int* __restrict__ deg, int* incl, int* partial) {
  __shared__ int s[SCAN_CH];
  int tid = threadIdx.x;
  int i = blockIdx.x * SCAN_CH + tid;
  int v = (i < N_NODES) ? deg[i] : 0;
  s[tid] = v;
  for (int off = 1; off < SCAN_CH; off <<= 1) {
    __syncthreads();
    int x = (tid >= off) ? s[tid - off] : 0;
    __syncthreads();
    s[tid] += x;
  }
  __syncthreads();
  if (i < N_NODES) incl[i] = s[tid];
  if (tid == SCAN_CH - 1) partial[blockIdx.x] = s[tid];
}

__global__ void k_scan2(const int* __restrict__ partial, int* chunk_off, int* row_ptr) {
  if (threadIdx.x == 0 && blockIdx.x == 0) {
    int run = 0;
    for (int b = 0; b < NCH; b++) { chunk_off[b] = run; run += partial[b]; }
    row_ptr[N_NODES] = run;   // == N_EDGES
  }
}

__global__ void k_scan3(const int* __restrict__ deg, const int* __restrict__ incl,
                        const int* __restrict__ chunk_off, int* row_ptr, int* cursor) {
  int i = blockIdx.x * SCAN_CH + threadIdx.x;
  if (i < N_NODES) {
    int e = chunk_off[blockIdx.x] + incl[i] - deg[i];
    row_ptr[i] = e;
    cursor[i]  = e;
  }
}

// ---------- CSR fill (bucket by dst) ----------
__global__ void k_fill(const int* __restrict__ src, const int* __restrict__ dst,
                       int* cursor, int* csr_src) {
  int e = blockIdx.x * 256 + threadIdx.x;
  if (e < N_EDGES) {
    int p = atomicAdd(&cursor[dst[e]], 1);
    csr_src[p] = src[e];
  }
}

// ---------- convert features: xb[n,f] = bf16(in_feat[n,f] * out_norm[n]) ----------
// halves gather traffic (102 MB table, L3-resident) and folds the per-edge scale
__global__ void k_conv(const float* __restrict__ in_feat, const float* __restrict__ out_norm,
                       bf16_t* __restrict__ xb) {
  int node = blockIdx.x, tid = threadIdx.x;
  float on = out_norm[node];
  float4 v = *(const float4*)(in_feat + (size_t)node * IN_DIM + tid * 4);
  bf16x4_t o;
  o[0] = (bf16_t)(v.x * on); o[1] = (bf16_t)(v.y * on);
  o[2] = (bf16_t)(v.z * on); o[3] = (bf16_t)(v.w * on);
  *(bf16x4_t*)(xb + (size_t)node * IN_DIM + tid * 4) = o;   // normal store: warms L3 for k_agg1
}

// ---------- layer-1 aggregation on bf16 pre-scaled feats ----------
// 128 threads/block, bf16x8 (16B) per lane; 8-deep edge unroll; fp32 accum.
// aggb stores are NON-TEMPORAL so the 100 MB write stream doesn't evict xb from L3.
__global__ void k_agg1(const bf16_t* __restrict__ xb, const int* __restrict__ row_ptr,
                       const int* __restrict__ csr_src, const float* __restrict__ in_norm,
                       bf16_t* __restrict__ aggb) {
  int node = blockIdx.x;
  int tid = threadIdx.x;            // 0..127
  float acc[8];
#pragma unroll
  for (int j = 0; j < 8; j++) acc[j] = 0.f;
  float inn = 0.f;
  if (node < N_NODES) {
    int beg = row_ptr[node], end = row_ptr[node + 1];
    int e = beg;
    for (; e + 8 <= end; e += 8) {
      int s[8];
#pragma unroll
      for (int u = 0; u < 8; u++) s[u] = csr_src[e + u];
      bf16x8_t v[8];
#pragma unroll
      for (int u = 0; u < 8; u++)
        v[u] = *(const bf16x8_t*)(xb + (size_t)s[u] * IN_DIM + tid * 8);
#pragma unroll
      for (int u = 0; u < 8; u++)
#pragma unroll
        for (int j = 0; j < 8; j++) acc[j] += (float)v[u][j];
    }
    for (; e + 2 <= end; e += 2) {
      int s0 = csr_src[e], s1 = csr_src[e + 1];
      bf16x8_t v0 = *(const bf16x8_t*)(xb + (size_t)s0 * IN_DIM + tid * 8);
      bf16x8_t v1 = *(const bf16x8_t*)(xb + (size_t)s1 * IN_DIM + tid * 8);
#pragma unroll
      for (int j = 0; j < 8; j++) acc[j] += (float)v0[j];
#pragma unroll
      for (int j = 0; j < 8; j++) acc[j] += (float)v1[j];
    }
    if (e < end) {
      int s0 = csr_src[e];
      bf16x8_t v0 = *(const bf16x8_t*)(xb + (size_t)s0 * IN_DIM + tid * 8);
#pragma unroll
      for (int j = 0; j < 8; j++) acc[j] += (float)v0[j];
    }
    inn = in_norm[node];
  }
  bf16x8_t o;
#pragma unroll
  for (int j = 0; j < 8; j++) o[j] = (bf16_t)(acc[j] * inn);
  __builtin_nontemporal_store(o, (bf16x8_t*)(aggb + (size_t)node * IN_DIM + tid * 8));
}

// ---------- W1 [K=1024][N=2048] fp32 -> W1t [N][K] bf16, LDS-tiled transpose ----------
__global__ void k_w1t(const float* __restrict__ W1, bf16_t* __restrict__ W1t) {
  __shared__ float tile[32][33];
  int k0 = blockIdx.x * 32, n0 = blockIdx.y * 32;
  int tx = threadIdx.x & 31, ty = threadIdx.x >> 5;   // 32 x 8
#pragma unroll
  for (int r = 0; r < 32; r += 8)
    tile[ty + r][tx] = W1[(size_t)(k0 + ty + r) * HID + n0 + tx];
  __syncthreads();
#pragma unroll
  for (int r = 0; r < 32; r += 8)
    W1t[(size_t)(n0 + ty + r) * IN_DIM + k0 + tx] = (bf16_t)tile[tx][ty + r];
}

// ---------- GEMM1: h1 = relu(agg @ W1 + b1) + fused BN column stats ----------
// m97 structure: 128x128 tile, BK=32, 4 waves in 2x2, 16x16x32 MFMA, global_load_lds w=16.
// Grid: x = col-tile (16), y = row-tile (391) so the co-resident block window covers all
// col-tiles of few row-tiles -> A-tiles fetched once, re-read from L2/L3.
// C stores NON-TEMPORAL so the 205 MB h1 write stream doesn't evict A from L3.
__global__ void __launch_bounds__(256)
k_gemm1(const bf16_t* __restrict__ A, const bf16_t* __restrict__ Bt,
        const float* __restrict__ b1, bf16_t* __restrict__ C,
        float* __restrict__ colsum, float* __restrict__ colsq) {
  __shared__ bf16_t As[128 * 32];
  __shared__ bf16_t Bs[128 * 32];
  int t = threadIdx.x;
  const int m0 = blockIdx.y * 128, n0 = blockIdx.x * 128;

  // staging: thread t loads 16B: row = t>>2 (64 rows per inst), seg = t&3
  int lrow = t >> 2, lseg = t & 3;
  const bf16_t* aG0 = A + (size_t)(m0 + lrow) * IN_DIM + lseg * 8;
  const bf16_t* aG1 = aG0 + (size_t)64 * IN_DIM;
  const bf16_t* bG0 = Bt + (size_t)(n0 + lrow) * IN_DIM + lseg * 8;
  const bf16_t* bG1 = bG0 + (size_t)64 * IN_DIM;
  bf16_t* aL0 = As + t * 8; bf16_t* aL1 = As + 2048 + t * 8;
  bf16_t* bL0 = Bs + t * 8; bf16_t* bL1 = Bs + 2048 + t * 8;

  // wave -> 64x64 quadrant; fragment addressing per m89-verified layout
  int wv = t >> 6, ln = t & 63;
  int wm = (wv >> 1) * 64, wn = (wv & 1) * 64;
  int fr = ln & 15, fq = ln >> 4;          // A row / B col = ln&15 ; k-quad = ln>>4
  const bf16_t* aF = As + (wm + fr) * 32 + fq * 8;
  const bf16_t* bF = Bs + (wn + fr) * 32 + fq * 8;

  f32x4_t acc[4][4];
#pragma unroll
  for (int i = 0; i < 4; i++)
#pragma unroll
    for (int j = 0; j < 4; j++) { acc[i][j][0]=0.f; acc[i][j][1]=0.f; acc[i][j][2]=0.f; acc[i][j][3]=0.f; }

  for (int kt = 0; kt < IN_DIM; kt += 32) {
    __syncthreads();                 // LDS reads of previous tile done
    gl2lds16(aG0 + kt, aL0);
    gl2lds16(aG1 + kt, aL1);
    gl2lds16(bG0 + kt, bL0);
    gl2lds16(bG1 + kt, bL1);
    __syncthreads();                 // compiler drains vmcnt before barrier
    bf16x8_t af[4], bfr[4];
#pragma unroll
    for (int i = 0; i < 4; i++) af[i]  = *(const bf16x8_t*)(aF + i * 16 * 32);
#pragma unroll
    for (int j = 0; j < 4; j++) bfr[j] = *(const bf16x8_t*)(bF + j * 16 * 32);
#pragma unroll
    for (int i = 0; i < 4; i++)
#pragma unroll
      for (int j = 0; j < 4; j++)
        acc[i][j] = __builtin_amdgcn_mfma_f32_16x16x32_bf16(af[i], bfr[j], acc[i][j], 0, 0, 0);
  }

  // epilogue: C/D layout col = ln&15, row = (ln>>4)*4 + reg ; +bias, relu, nt bf16 store,
  // fused BN column stats (masked to valid rows), xor-shuffle reduce over k-quads
#pragma unroll
  for (int j = 0; j < 4; j++) {
    int col = n0 + wn + j * 16 + fr;
    float bias = b1[col];
    float s = 0.f, ss = 0.f;
#pragma unroll
    for (int i = 0; i < 4; i++) {
#pragma unroll
      for (int r = 0; r < 4; r++) {
        int row = m0 + wm + i * 16 + fq * 4 + r;
        float v = acc[i][j][r] + bias;
        v = v > 0.f ? v : 0.f;
        bf16_t bv = (bf16_t)v;
        __builtin_nontemporal_store(*(short*)&bv, (short*)&C[(size_t)row * HID + col]);
        if (row < N_NODES) { s += v; ss += v * v; }
      }
    }
    s  += __shfl_xor(s, 16);  s  += __shfl_xor(s, 32);
    ss += __shfl_xor(ss, 16); ss += __shfl_xor(ss, 32);
    if (fq == 0) {
      atomicAdd(&colsum[col], s);
      atomicAdd(&colsq[col], ss);
    }
  }
}

// ---------- fold BN into Wout: cw[f,o] = rs[f]*Wout[f,o]; mrs[f] = mean[f]*rs[f] ----------
__global__ void k_bnfin(const float* __restrict__ colsum, const float* __restrict__ colsq,
                        const float* __restrict__ Wout,
                        float* cw0, float* cw1, float* cw2, float* mrs) {
  int f = blockIdx.x * 256 + threadIdx.x;
  if (f < HID) {
    float mean = colsum[f] * (1.f / N_NODES);
    float var  = colsq[f] * (1.f / N_NODES) - mean * mean;
    float rs   = rsqrtf(var + BN_EPS);
    cw0[f] = rs * Wout[f * 3 + 0];
    cw1[f] = rs * Wout[f * 3 + 1];
    cw2[f] = rs * Wout[f * 3 + 2];
    mrs[f] = mean * rs;
  }
}

// ---------- ct[o] = sum_f mrs[f]*Wout[f,o] ----------
__global__ void k_ct(const float* __restrict__ mrs, const float* __restrict__ Wout, float* ct) {
  __shared__ float red[3][256];
  int tid = threadIdx.x;
  float s0 = 0.f, s1 = 0.f, s2 = 0.f;
  for (int f = tid; f < HID; f += 256) {
    float m = mrs[f];
    s0 += m * Wout[f * 3 + 0];
    s1 += m * Wout[f * 3 + 1];
    s2 += m * Wout[f * 3 + 2];
  }
  red[0][tid] = s0; red[1][tid] = s1; red[2][tid] = s2;
  __syncthreads();
  for (int off = 128; off; off >>= 1) {
    if (tid < off) {
      red[0][tid] += red[0][tid + off];
      red[1][tid] += red[1][tid + off];
      red[2][tid] += red[2][tid + off];
    }
    __syncthreads();
  }
  if (tid == 0) { ct[0] = red[0][0]; ct[1] = red[1][0]; ct[2] = red[2][0]; }
}

// ---------- t[n] = out_norm[n] * (h_bn[n] @ Wout) via cw/ct ----------
__global__ void k_tmat(const bf16_t* __restrict__ h1, const float* __restrict__ cw0,
                       const float* __restrict__ cw1, const float* __restrict__ cw2,
                       const float* __restrict__ ct, const float* __restrict__ out_norm,
                       float4* __restrict__ t4) {
  int n = blockIdx.x, tid = threadIdx.x;
  int f0 = tid * 8;
  bf16x8_t hv = *(const bf16x8_t*)(h1 + (size_t)n * HID + f0);
  float s0 = 0.f, s1 = 0.f, s2 = 0.f;
#pragma unroll
  for (int j = 0; j < 8; j++) {
    float h = (float)hv[j];
    s0 += h * cw0[f0 + j];
    s1 += h * cw1[f0 + j];
    s2 += h * cw2[f0 + j];
  }
#pragma unroll
  for (int off = 32; off; off >>= 1) {
    s0 += __shfl_down(s0, off);
    s1 += __shfl_down(s1, off);
    s2 += __shfl_down(s2, off);
  }
  __shared__ float red[3][4];
  int wv = tid >> 6, ln = tid & 63;
  if (ln == 0) { red[0][wv] = s0; red[1][wv] = s1; red[2][wv] = s2; }
  __syncthreads();
  if (tid == 0) {
    float r0 = red[0][0] + red[0][1] + red[0][2] + red[0][3];
    float r1 = red[1][0] + red[1][1] + red[1][2] + red[1][3];
    float r2 = red[2][0] + red[2][1] + red[2][2] + red[2][3];
    float on = out_norm[n];
    t4[n] = make_float4(on * (r0 - ct[0]), on * (r1 - ct[1]), on * (r2 - ct[2]), 0.f);
  }
}

// ---------- layer-2 aggregation (3 feats) + bias + softmax ----------
__global__ void k_out(const int* __restrict__ row_ptr, const int* __restrict__ csr_src,
                      const float4* __restrict__ t4, const float* __restrict__ in_norm,
                      const float* __restrict__ bout, float* __restrict__ out) {
  int i = blockIdx.x * 256 + threadIdx.x;
  if (i >= N_NODES) return;
  float a0 = 0.f, a1 = 0.f, a2 = 0.f;
  int beg = row_ptr[i], end = row_ptr[i + 1];
  for (int e = beg; e < end; e++) {
    float4 tv = t4[csr_src[e]];
    a0 += tv.x; a1 += tv.y; a2 += tv.z;
  }
  float inn = in_norm[i];
  float l0 = inn * a0 + bout[0];
  float l1 = inn * a1 + bout[1];
  float l2 = inn * a2 + bout[2];
  float m = fmaxf(l0, fmaxf(l1, l2));
  float e0 = expf(l0 - m), e1 = expf(l1 - m), e2 = expf(l2 - m);
  float rs = 1.f / (e0 + e1 + e2);
  out[i * 3 + 0] = e0 * rs;
  out[i * 3 + 1] = e1 * rs;
  out[i * 3 + 2] = e2 * rs;
}

extern "C" void kernel_launch(void* const* d_in, const int* in_sizes, int n_in,
                              void* d_out, int out_size, void* d_ws, size_t ws_size,
                              hipStream_t stream) {
  const float* in_feat = (const float*)d_in[0];
  const int*   src     = (const int*)d_in[1];
  const int*   dst     = (const int*)d_in[2];
  const float* W1      = (const float*)d_in[3];
  const float* b1      = (const float*)d_in[4];
  const float* Wout    = (const float*)d_in[5];
  const float* bout    = (const float*)d_in[6];
  float* out = (float*)d_out;

  char* p = (char*)d_ws;
  auto alloc = [&](size_t bytes) { char* r = p; p += (bytes + 255) & ~(size_t)255; return r; };
  bf16_t* h1      = (bf16_t*)alloc((size_t)M_PAD * HID * 2);      // 205 MB
  bf16_t* aggb    = (bf16_t*)alloc((size_t)M_PAD * IN_DIM * 2);   // 102.5 MB
  bf16_t* xb      = (bf16_t*)alloc((size_t)N_NODES * IN_DIM * 2); // 102.4 MB
  bf16_t* W1t     = (bf16_t*)alloc((size_t)HID * IN_DIM * 2);     // 4 MB
  int* csr_src    = (int*)alloc((size_t)N_EDGES * 4);             // 6.4 MB
  int* row_ptr    = (int*)alloc((size_t)(N_NODES + 1) * 4);
  int* cursor     = (int*)alloc((size_t)N_NODES * 4);
  int* incl       = (int*)alloc((size_t)N_NODES * 4);
  int* partial    = (int*)alloc((size_t)NCH * 4);
  int* chunk_off  = (int*)alloc((size_t)NCH * 4);
  int* out_cnt    = (int*)alloc((size_t)N_NODES * 4);
  int* in_cnt     = (int*)alloc((size_t)N_NODES * 4);
  float* out_norm = (float*)alloc((size_t)N_NODES * 4);
  float* in_norm  = (float*)alloc((size_t)N_NODES * 4);
  float* colsum   = (float*)alloc((size_t)HID * 4);
  float* colsq    = (float*)alloc((size_t)HID * 4);
  float* cw0      = (float*)alloc((size_t)HID * 4);
  float* cw1      = (float*)alloc((size_t)HID * 4);
  float* cw2      = (float*)alloc((size_t)HID * 4);
  float* mrs      = (float*)alloc((size_t)HID * 4);
  float* ct       = (float*)alloc(4 * 4);
  float4* t4      = (float4*)alloc((size_t)N_NODES * 16);

  // ws is poisoned 0xAA each call — zero what needs zeroing
  hipMemsetAsync(out_cnt, 0, (size_t)N_NODES * 4, stream);
  hipMemsetAsync(in_cnt,  0, (size_t)N_NODES * 4, stream);
  hipMemsetAsync(colsum,  0, (size_t)HID * 4, stream);
  hipMemsetAsync(colsq,   0, (size_t)HID * 4, stream);

  k_hist <<<(N_EDGES + 255) / 256, 256, 0, stream>>>(src, dst, out_cnt, in_cnt);
  k_norms<<<(N_NODES + 255) / 256, 256, 0, stream>>>(out_cnt, in_cnt, out_norm, in_norm);
  k_conv <<<N_NODES, 256, 0, stream>>>(in_feat, out_norm, xb);
  k_scan1<<<NCH, SCAN_CH, 0, stream>>>(in_cnt, incl, partial);
  k_scan2<<<1, 64, 0, stream>>>(partial, chunk_off, row_ptr);
  k_scan3<<<NCH, SCAN_CH, 0, stream>>>(in_cnt, incl, chunk_off, row_ptr, cursor);
  k_fill <<<(N_EDGES + 255) / 256, 256, 0, stream>>>(src, dst, cursor, csr_src);
  k_w1t  <<<dim3(IN_DIM / 32, HID / 32), 256, 0, stream>>>(W1, W1t);
  k_agg1 <<<M_PAD, 128, 0, stream>>>(xb, row_ptr, csr_src, in_norm, aggb);
  k_gemm1<<<dim3(HID / 128, M_PAD / 128), 256, 0, stream>>>(aggb, W1t, b1, h1, colsum, colsq);
  k_bnfin<<<HID / 256, 256, 0, stream>>>(colsum, colsq, Wout, cw0, cw1, cw2, mrs);
  k_ct   <<<1, 256, 0, stream>>>(mrs, Wout, ct);
  k_tmat <<<N_NODES, 256, 0, stream>>>(h1, cw0, cw1, cw2, ct, out_norm, t4);
  k_out  <<<(N_NODES + 255) / 256, 256, 0, stream>>>(row_ptr, csr_src, t4, in_norm, bout, out);
}

// Round 5
// 1445.854 us; speedup vs baseline: 1.4852x; 1.0125x over previous
//
#include <hip/hip_runtime.h>
#include <hip/hip_bf16.h>
#include <stdint.h>

// Problem constants (fixed by the reference)
#define N_NODES 50000
#define N_EDGES 1600000
#define IN_DIM  1024
#define HID     2048
#define OUTC    3
#define M_PAD   50048   // 391 * 128 — M padded to GEMM tile
#define BN_EPS  1e-5f

#define SCAN_CH 512
#define NCH     98      // ceil(50000/512)

// agg1 feature panels: 2 x 512 feats -> 51 MB random working set per phase (20% of L3)
#define NPANEL  2
#define PFEAT   512

typedef __bf16 bf16_t;
typedef __bf16 bf16x4_t __attribute__((ext_vector_type(4)));
typedef __bf16 bf16x8_t __attribute__((ext_vector_type(8)));
typedef float  f32x4_t  __attribute__((ext_vector_type(4)));

// async global->LDS, 16B per lane. LDS layout must be contiguous in lane order.
__device__ __forceinline__ void gl2lds16(const void* g, void* l) {
  __builtin_amdgcn_global_load_lds((const __attribute__((address_space(1))) uint32_t*)g,
                                   (__attribute__((address_space(3))) uint32_t*)l,
                                   16, 0, 0);
}

// ---------- degree histograms ----------
__global__ void k_hist(const int* __restrict__ src, const int* __restrict__ dst,
                       int* out_cnt, int* in_cnt) {
  int e = blockIdx.x * 256 + threadIdx.x;
  if (e < N_EDGES) {
    atomicAdd(&out_cnt[src[e]], 1);
    atomicAdd(&in_cnt[dst[e]], 1);
  }
}

// ---------- degree norms: clip(deg,1)^-0.5 ----------
__global__ void k_norms(const int* __restrict__ out_cnt, const int* __restrict__ in_cnt,
                        float* out_norm, float* in_norm) {
  int i = blockIdx.x * 256 + threadIdx.x;
  if (i < N_NODES) {
    out_norm[i] = rsqrtf((float)max(out_cnt[i], 1));
    in_norm[i]  = rsqrtf((float)max(in_cnt[i], 1));
  }
}

// ---------- exclusive scan of in-degrees (3-phase) ----------
__global__ void k_scan1(const int* __restrict__ deg, int* incl, int* partial) {
  __shared__ int s[SCAN_CH];
  int tid = threadIdx.x;
  int i = blockIdx.x * SCAN_CH + tid;
  int v = (i < N_NODES) ? deg[i] : 0;
  s[tid] = v;
  for (int off = 1; off < SCAN_CH; off <<= 1) {
    __syncthreads();
    int x = (tid >= off) ? s[tid - off] : 0;
    __syncthreads();
    s[tid] += x;
  }
  __syncthreads();
  if (i < N_NODES) incl[i] = s[tid];
  if (tid == SCAN_CH - 1) partial[blockIdx.x] = s[tid];
}

__global__ void k_scan2(const int* __restrict__ partial, int* chunk_off, int* row_ptr) {
  if (threadIdx.x == 0 && blockIdx.x == 0) {
    int run = 0;
    for (int b = 0; b < NCH; b++) { chunk_off[b] = run; run += partial[b]; }
    row_ptr[N_NODES] = run;   // == N_EDGES
  }
}

__global__ void k_scan3(const int* __restrict__ deg, const int* __restrict__ incl,
                        const int* __restrict__ chunk_off, int* row_ptr, int* cursor) {
  int i = blockIdx.x * SCAN_CH + threadIdx.x;
  if (i < N_NODES) {
    int e = chunk_off[blockIdx.x] + incl[i] - deg[i];
    row_ptr[i] = e;
    cursor[i]  = e;
  }
}

// ---------- CSR fill (bucket by dst) ----------
__global__ void k_fill(const int* __restrict__ src, const int* __restrict__ dst,
                       int* cursor, int* csr_src) {
  int e = blockIdx.x * 256 + threadIdx.x;
  if (e < N_EDGES) {
    int p = atomicAdd(&cursor[dst[e]], 1);
    csr_src[p] = src[e];
  }
}

// ---------- convert features: xb[n,f] = bf16(in_feat[n,f] * out_norm[n]) ----------
// halves gather traffic and folds the per-edge scale
__global__ void k_conv(const float* __restrict__ in_feat, const float* __restrict__ out_norm,
                       bf16_t* __restrict__ xb) {
  int node = blockIdx.x, tid = threadIdx.x;
  float on = out_norm[node];
  float4 v = *(const float4*)(in_feat + (size_t)node * IN_DIM + tid * 4);
  bf16x4_t o;
  o[0] = (bf16_t)(v.x * on); o[1] = (bf16_t)(v.y * on);
  o[2] = (bf16_t)(v.z * on); o[3] = (bf16_t)(v.w * on);
  *(bf16x4_t*)(xb + (size_t)node * IN_DIM + tid * 4) = o;
}

// ---------- layer-1 aggregation, feature-panel phased ----------
// grid = (M_PAD/2, NPANEL); 128 threads = 2 waves = 2 nodes of the SAME panel.
// Each wave: 64 lanes x bf16x8 = 512 feats (one panel) of its node; 8-deep edge unroll.
// Panel phasing keeps the random working set at 51 MB -> L3-resident.
__global__ void k_agg1(const bf16_t* __restrict__ xb, const int* __restrict__ row_ptr,
                       const int* __restrict__ csr_src, const float* __restrict__ in_norm,
                       bf16_t* __restrict__ aggb) {
  int node = blockIdx.x * 2 + (threadIdx.x >> 6);
  int lane = threadIdx.x & 63;
  int f0 = blockIdx.y * PFEAT + lane * 8;
  float acc[8];
#pragma unroll
  for (int j = 0; j < 8; j++) acc[j] = 0.f;
  float inn = 0.f;
  if (node < N_NODES) {
    int beg = row_ptr[node], end = row_ptr[node + 1];
    int e = beg;
    for (; e + 8 <= end; e += 8) {
      int s[8];
#pragma unroll
      for (int u = 0; u < 8; u++) s[u] = csr_src[e + u];
      bf16x8_t v[8];
#pragma unroll
      for (int u = 0; u < 8; u++)
        v[u] = *(const bf16x8_t*)(xb + (size_t)s[u] * IN_DIM + f0);
#pragma unroll
      for (int u = 0; u < 8; u++)
#pragma unroll
        for (int j = 0; j < 8; j++) acc[j] += (float)v[u][j];
    }
    for (; e + 2 <= end; e += 2) {
      int s0 = csr_src[e], s1 = csr_src[e + 1];
      bf16x8_t v0 = *(const bf16x8_t*)(xb + (size_t)s0 * IN_DIM + f0);
      bf16x8_t v1 = *(const bf16x8_t*)(xb + (size_t)s1 * IN_DIM + f0);
#pragma unroll
      for (int j = 0; j < 8; j++) acc[j] += (float)v0[j];
#pragma unroll
      for (int j = 0; j < 8; j++) acc[j] += (float)v1[j];
    }
    if (e < end) {
      int s0 = csr_src[e];
      bf16x8_t v0 = *(const bf16x8_t*)(xb + (size_t)s0 * IN_DIM + f0);
#pragma unroll
      for (int j = 0; j < 8; j++) acc[j] += (float)v0[j];
    }
    inn = in_norm[node];
  }
  bf16x8_t o;
#pragma unroll
  for (int j = 0; j < 8; j++) o[j] = (bf16_t)(acc[j] * inn);
  __builtin_nontemporal_store(o, (bf16x8_t*)(aggb + (size_t)node * IN_DIM + f0));
}

// ---------- W1 [K=1024][N=2048] fp32 -> W1t [N][K] bf16, LDS-tiled transpose ----------
__global__ void k_w1t(const float* __restrict__ W1, bf16_t* __restrict__ W1t) {
  __shared__ float tile[32][33];
  int k0 = blockIdx.x * 32, n0 = blockIdx.y * 32;
  int tx = threadIdx.x & 31, ty = threadIdx.x >> 5;   // 32 x 8
#pragma unroll
  for (int r = 0; r < 32; r += 8)
    tile[ty + r][tx] = W1[(size_t)(k0 + ty + r) * HID + n0 + tx];
  __syncthreads();
#pragma unroll
  for (int r = 0; r < 32; r += 8)
    W1t[(size_t)(n0 + ty + r) * IN_DIM + k0 + tx] = (bf16_t)tile[tx][ty + r];
}

// ---------- GEMM1: h1 = relu(agg @ W1 + b1) + fused BN column stats ----------
// m97 structure: 128x128 tile, BK=32, 4 waves in 2x2, 16x16x32 MFMA, global_load_lds w=16.
// Grid: x = col-tile (16), y = row-tile (391); C stores non-temporal.
__global__ void __launch_bounds__(256)
k_gemm1(const bf16_t* __restrict__ A, const bf16_t* __restrict__ Bt,
        const float* __restrict__ b1, bf16_t* __restrict__ C,
        float* __restrict__ colsum, float* __restrict__ colsq) {
  __shared__ bf16_t As[128 * 32];
  __shared__ bf16_t Bs[128 * 32];
  int t = threadIdx.x;
  const int m0 = blockIdx.y * 128, n0 = blockIdx.x * 128;

  // staging: thread t loads 16B: row = t>>2 (64 rows per inst), seg = t&3
  int lrow = t >> 2, lseg = t & 3;
  const bf16_t* aG0 = A + (size_t)(m0 + lrow) * IN_DIM + lseg * 8;
  const bf16_t* aG1 = aG0 + (size_t)64 * IN_DIM;
  const bf16_t* bG0 = Bt + (size_t)(n0 + lrow) * IN_DIM + lseg * 8;
  const bf16_t* bG1 = bG0 + (size_t)64 * IN_DIM;
  bf16_t* aL0 = As + t * 8; bf16_t* aL1 = As + 2048 + t * 8;
  bf16_t* bL0 = Bs + t * 8; bf16_t* bL1 = Bs + 2048 + t * 8;

  // wave -> 64x64 quadrant; fragment addressing per m89-verified layout
  int wv = t >> 6, ln = t & 63;
  int wm = (wv >> 1) * 64, wn = (wv & 1) * 64;
  int fr = ln & 15, fq = ln >> 4;          // A row / B col = ln&15 ; k-quad = ln>>4
  const bf16_t* aF = As + (wm + fr) * 32 + fq * 8;
  const bf16_t* bF = Bs + (wn + fr) * 32 + fq * 8;

  f32x4_t acc[4][4];
#pragma unroll
  for (int i = 0; i < 4; i++)
#pragma unroll
    for (int j = 0; j < 4; j++) { acc[i][j][0]=0.f; acc[i][j][1]=0.f; acc[i][j][2]=0.f; acc[i][j][3]=0.f; }

  for (int kt = 0; kt < IN_DIM; kt += 32) {
    __syncthreads();                 // LDS reads of previous tile done
    gl2lds16(aG0 + kt, aL0);
    gl2lds16(aG1 + kt, aL1);
    gl2lds16(bG0 + kt, bL0);
    gl2lds16(bG1 + kt, bL1);
    __syncthreads();                 // compiler drains vmcnt before barrier
    bf16x8_t af[4], bfr[4];
#pragma unroll
    for (int i = 0; i < 4; i++) af[i]  = *(const bf16x8_t*)(aF + i * 16 * 32);
#pragma unroll
    for (int j = 0; j < 4; j++) bfr[j] = *(const bf16x8_t*)(bF + j * 16 * 32);
#pragma unroll
    for (int i = 0; i < 4; i++)
#pragma unroll
      for (int j = 0; j < 4; j++)
        acc[i][j] = __builtin_amdgcn_mfma_f32_16x16x32_bf16(af[i], bfr[j], acc[i][j], 0, 0, 0);
  }

  // epilogue: C/D layout col = ln&15, row = (ln>>4)*4 + reg ; +bias, relu, nt bf16 store,
  // fused BN column stats (masked to valid rows), xor-shuffle reduce over k-quads
#pragma unroll
  for (int j = 0; j < 4; j++) {
    int col = n0 + wn + j * 16 + fr;
    float bias = b1[col];
    float s = 0.f, ss = 0.f;
#pragma unroll
    for (int i = 0; i < 4; i++) {
#pragma unroll
      for (int r = 0; r < 4; r++) {
        int row = m0 + wm + i * 16 + fq * 4 + r;
        float v = acc[i][j][r] + bias;
        v = v > 0.f ? v : 0.f;
        bf16_t bv = (bf16_t)v;
        __builtin_nontemporal_store(*(short*)&bv, (short*)&C[(size_t)row * HID + col]);
        if (row < N_NODES) { s += v; ss += v * v; }
      }
    }
    s  += __shfl_xor(s, 16);  s  += __shfl_xor(s, 32);
    ss += __shfl_xor(ss, 16); ss += __shfl_xor(ss, 32);
    if (fq == 0) {
      atomicAdd(&colsum[col], s);
      atomicAdd(&colsq[col], ss);
    }
  }
}

// ---------- fold BN into Wout: cw[f,o] = rs[f]*Wout[f,o]; mrs[f] = mean[f]*rs[f] ----------
__global__ void k_bnfin(const float* __restrict__ colsum, const float* __restrict__ colsq,
                        const float* __restrict__ Wout,
                        float* cw0, float* cw1, float* cw2, float* mrs) {
  int f = blockIdx.x * 256 + threadIdx.x;
  if (f < HID) {
    float mean = colsum[f] * (1.f / N_NODES);
    float var  = colsq[f] * (1.f / N_NODES) - mean * mean;
    float rs   = rsqrtf(var + BN_EPS);
    cw0[f] = rs * Wout[f * 3 + 0];
    cw1[f] = rs * Wout[f * 3 + 1];
    cw2[f] = rs * Wout[f * 3 + 2];
    mrs[f] = mean * rs;
  }
}

// ---------- ct[o] = sum_f mrs[f]*Wout[f,o] ----------
__global__ void k_ct(const float* __restrict__ mrs, const float* __restrict__ Wout, float* ct) {
  __shared__ float red[3][256];
  int tid = threadIdx.x;
  float s0 = 0.f, s1 = 0.f, s2 = 0.f;
  for (int f = tid; f < HID; f += 256) {
    float m = mrs[f];
    s0 += m * Wout[f * 3 + 0];
    s1 += m * Wout[f * 3 + 1];
    s2 += m * Wout[f * 3 + 2];
  }
  red[0][tid] = s0; red[1][tid] = s1; red[2][tid] = s2;
  __syncthreads();
  for (int off = 128; off; off >>= 1) {
    if (tid < off) {
      red[0][tid] += red[0][tid + off];
      red[1][tid] += red[1][tid + off];
      red[2][tid] += red[2][tid + off];
    }
    __syncthreads();
  }
  if (tid == 0) { ct[0] = red[0][0]; ct[1] = red[1][0]; ct[2] = red[2][0]; }
}

// ---------- t[n] = out_norm[n] * (h_bn[n] @ Wout) via cw/ct ----------
__global__ void k_tmat(const bf16_t* __restrict__ h1, const float* __restrict__ cw0,
                       const float* __restrict__ cw1, const float* __restrict__ cw2,
                       const float* __restrict__ ct, const float* __restrict__ out_norm,
                       float4* __restrict__ t4) {
  int n = blockIdx.x, tid = threadIdx.x;
  int f0 = tid * 8;
  bf16x8_t hv = *(const bf16x8_t*)(h1 + (size_t)n * HID + f0);
  float s0 = 0.f, s1 = 0.f, s2 = 0.f;
#pragma unroll
  for (int j = 0; j < 8; j++) {
    float h = (float)hv[j];
    s0 += h * cw0[f0 + j];
    s1 += h * cw1[f0 + j];
    s2 += h * cw2[f0 + j];
  }
#pragma unroll
  for (int off = 32; off; off >>= 1) {
    s0 += __shfl_down(s0, off);
    s1 += __shfl_down(s1, off);
    s2 += __shfl_down(s2, off);
  }
  __shared__ float red[3][4];
  int wv = tid >> 6, ln = tid & 63;
  if (ln == 0) { red[0][wv] = s0; red[1][wv] = s1; red[2][wv] = s2; }
  __syncthreads();
  if (tid == 0) {
    float r0 = red[0][0] + red[0][1] + red[0][2] + red[0][3];
    float r1 = red[1][0] + red[1][1] + red[1][2] + red[1][3];
    float r2 = red[2][0] + red[2][1] + red[2][2] + red[2][3];
    float on = out_norm[n];
    t4[n] = make_float4(on * (r0 - ct[0]), on * (r1 - ct[1]), on * (r2 - ct[2]), 0.f);
  }
}

// ---------- layer-2 aggregation (3 feats) + bias + softmax ----------
__global__ void k_out(const int* __restrict__ row_ptr, const int* __restrict__ csr_src,
                      const float4* __restrict__ t4, const float* __restrict__ in_norm,
                      const float* __restrict__ bout, float* __restrict__ out) {
  int i = blockIdx.x * 256 + threadIdx.x;
  if (i >= N_NODES) return;
  float a0 = 0.f, a1 = 0.f, a2 = 0.f;
  int beg = row_ptr[i], end = row_ptr[i + 1];
  for (int e = beg; e < end; e++) {
    float4 tv = t4[csr_src[e]];
    a0 += tv.x; a1 += tv.y; a2 += tv.z;
  }
  float inn = in_norm[i];
  float l0 = inn * a0 + bout[0];
  float l1 = inn * a1 + bout[1];
  float l2 = inn * a2 + bout[2];
  float m = fmaxf(l0, fmaxf(l1, l2));
  float e0 = expf(l0 - m), e1 = expf(l1 - m), e2 = expf(l2 - m);
  float rs = 1.f / (e0 + e1 + e2);
  out[i * 3 + 0] = e0 * rs;
  out[i * 3 + 1] = e1 * rs;
  out[i * 3 + 2] = e2 * rs;
}

extern "C" void kernel_launch(void* const* d_in, const int* in_sizes, int n_in,
                              void* d_out, int out_size, void* d_ws, size_t ws_size,
                              hipStream_t stream) {
  const float* in_feat = (const float*)d_in[0];
  const int*   src     = (const int*)d_in[1];
  const int*   dst     = (const int*)d_in[2];
  const float* W1      = (const float*)d_in[3];
  const float* b1      = (const float*)d_in[4];
  const float* Wout    = (const float*)d_in[5];
  const float* bout    = (const float*)d_in[6];
  float* out = (float*)d_out;

  char* p = (char*)d_ws;
  auto alloc = [&](size_t bytes) { char* r = p; p += (bytes + 255) & ~(size_t)255; return r; };
  bf16_t* h1      = (bf16_t*)alloc((size_t)M_PAD * HID * 2);      // 205 MB
  bf16_t* aggb    = (bf16_t*)alloc((size_t)M_PAD * IN_DIM * 2);   // 102.5 MB
  bf16_t* xb      = (bf16_t*)alloc((size_t)N_NODES * IN_DIM * 2); // 102.4 MB
  bf16_t* W1t     = (bf16_t*)alloc((size_t)HID * IN_DIM * 2);     // 4 MB
  int* csr_src    = (int*)alloc((size_t)N_EDGES * 4);             // 6.4 MB
  int* row_ptr    = (int*)alloc((size_t)(N_NODES + 1) * 4);
  int* cursor     = (int*)alloc((size_t)N_NODES * 4);
  int* incl       = (int*)alloc((size_t)N_NODES * 4);
  int* partial    = (int*)alloc((size_t)NCH * 4);
  int* chunk_off  = (int*)alloc((size_t)NCH * 4);
  int* out_cnt    = (int*)alloc((size_t)N_NODES * 4);
  int* in_cnt     = (int*)alloc((size_t)N_NODES * 4);
  float* out_norm = (float*)alloc((size_t)N_NODES * 4);
  float* in_norm  = (float*)alloc((size_t)N_NODES * 4);
  float* colsum   = (float*)alloc((size_t)HID * 4);
  float* colsq    = (float*)alloc((size_t)HID * 4);
  float* cw0      = (float*)alloc((size_t)HID * 4);
  float* cw1      = (float*)alloc((size_t)HID * 4);
  float* cw2      = (float*)alloc((size_t)HID * 4);
  float* mrs      = (float*)alloc((size_t)HID * 4);
  float* ct       = (float*)alloc(4 * 4);
  float4* t4      = (float4*)alloc((size_t)N_NODES * 16);

  // ws is poisoned 0xAA each call — zero what needs zeroing
  hipMemsetAsync(out_cnt, 0, (size_t)N_NODES * 4, stream);
  hipMemsetAsync(in_cnt,  0, (size_t)N_NODES * 4, stream);
  hipMemsetAsync(colsum,  0, (size_t)HID * 4, stream);
  hipMemsetAsync(colsq,   0, (size_t)HID * 4, stream);

  k_hist <<<(N_EDGES + 255) / 256, 256, 0, stream>>>(src, dst, out_cnt, in_cnt);
  k_norms<<<(N_NODES + 255) / 256, 256, 0, stream>>>(out_cnt, in_cnt, out_norm, in_norm);
  k_conv <<<N_NODES, 256, 0, stream>>>(in_feat, out_norm, xb);
  k_scan1<<<NCH, SCAN_CH, 0, stream>>>(in_cnt, incl, partial);
  k_scan2<<<1, 64, 0, stream>>>(partial, chunk_off, row_ptr);
  k_scan3<<<NCH, SCAN_CH, 0, stream>>>(in_cnt, incl, chunk_off, row_ptr, cursor);
  k_fill <<<(N_EDGES + 255) / 256, 256, 0, stream>>>(src, dst, cursor, csr_src);
  k_w1t  <<<dim3(IN_DIM / 32, HID / 32), 256, 0, stream>>>(W1, W1t);
  k_agg1 <<<dim3(M_PAD / 2, NPANEL), 128, 0, stream>>>(xb, row_ptr, csr_src, in_norm, aggb);
  k_gemm1<<<dim3(HID / 128, M_PAD / 128), 256, 0, stream>>>(aggb, W1t, b1, h1, colsum, colsq);
  k_bnfin<<<HID / 256, 256, 0, stream>>>(colsum, colsq, Wout, cw0, cw1, cw2, mrs);
  k_ct   <<<1, 256, 0, stream>>>(mrs, Wout, ct);
  k_tmat <<<N_NODES, 256, 0, stream>>>(h1, cw0, cw1, cw2, ct, out_norm, t4);
  k_out  <<<(N_NODES + 255) / 256, 256, 0, stream>>>(row_ptr, csr_src, t4, in_norm, bout, out);
}